// Round 4
// baseline (2131.698 us; speedup 1.0000x reference)
//
#include <hip/hip_runtime.h>
#include <math.h>

namespace {

constexpr int kT = 128, kB = 512, kD = 512, kM = 6, kH = 2;
constexpr int kJ = kT + kM;          // 134
constexpr float kBG = 0.1f;
constexpr int kTB = kT * kB;         // 65536 rows
constexpr int kBK = 32;              // K-tile for MFMA kernels

typedef __attribute__((ext_vector_type(8))) short bf16x8;
typedef __attribute__((ext_vector_type(4))) float f32x4;
typedef __attribute__((ext_vector_type(8))) unsigned short us8;

__device__ __forceinline__ float sigmoidf_(float x) {
  return 1.0f / (1.0f + __expf(-x));
}

__device__ __forceinline__ unsigned short bf16u(float f) {
  union { float f; unsigned u; } c; c.f = f;
  unsigned r = c.u + 0x7fffu + ((c.u >> 16) & 1u);
  return (unsigned short)(r >> 16);
}

__device__ __forceinline__ float b2f(unsigned short u) {
  union { unsigned u; float f; } c; c.u = (unsigned)u << 16;
  return c.f;
}

__device__ __forceinline__ void gl_lds16(const void* g, void* l) {
  __builtin_amdgcn_global_load_lds(
      (const __attribute__((address_space(1))) unsigned int*)g,
      (__attribute__((address_space(3))) unsigned int*)l, 16, 0, 0);
}

// ---- transpose + cast: W fp32 [K][N] -> Wt bf16 [N][K]; dims mult of 32 ----
__global__ __launch_bounds__(256) void transp_kernel(const float* __restrict__ W,
                                                     unsigned short* __restrict__ Wt,
                                                     int K, int N) {
  __shared__ float t[32][33];
  const int n0 = blockIdx.x * 32, k0 = blockIdx.y * 32;
  const float* Wb = W + (size_t)blockIdx.z * K * N;
  unsigned short* Wtb = Wt + (size_t)blockIdx.z * K * N;
  int tx = threadIdx.x & 31, ty = threadIdx.x >> 5;  // 32 x 8
#pragma unroll
  for (int r = 0; r < 32; r += 8)
    t[ty + r][tx] = Wb[(size_t)(k0 + ty + r) * N + n0 + tx];
  __syncthreads();
#pragma unroll
  for (int r = 0; r < 32; r += 8)
    Wtb[(size_t)(n0 + ty + r) * K + k0 + tx] = bf16u(t[tx][ty + r]);
}

// ---- fp32 -> bf16 elementwise (n multiple of 8) ----
__global__ __launch_bounds__(256) void conv_bf16_kernel(const float* __restrict__ in,
                                                        unsigned short* __restrict__ outb,
                                                        size_t n) {
  size_t idx = ((size_t)blockIdx.x * 256 + threadIdx.x) * 8;
  if (idx >= n) return;
  float4 a = *(const float4*)(in + idx);
  float4 c = *(const float4*)(in + idx + 4);
  us8 o;
  o[0] = bf16u(a.x); o[1] = bf16u(a.y); o[2] = bf16u(a.z); o[3] = bf16u(a.w);
  o[4] = bf16u(c.x); o[5] = bf16u(c.y); o[6] = bf16u(c.z); o[7] = bf16u(c.w);
  *(us8*)(outb + idx) = o;
}

// ---- LN1 dual-output: LN(x) -> bf16 AND raw x -> bf16, one fp32 read ----
__global__ __launch_bounds__(256) void ln1_dual_kernel(const float* __restrict__ in,
                                                       const float* __restrict__ g,
                                                       const float* __restrict__ b,
                                                       unsigned short* __restrict__ outLN,
                                                       unsigned short* __restrict__ outRaw,
                                                       int nrows) {
  int wave = threadIdx.x >> 6, lane = threadIdx.x & 63;
  int row = blockIdx.x * 4 + wave;
  if (row >= nrows) return;
  const float* p = in + (size_t)row * kD + lane * 8;
  float4 a = *(const float4*)p;
  float4 c = *(const float4*)(p + 4);
  float v[8] = {a.x, a.y, a.z, a.w, c.x, c.y, c.z, c.w};
  float s = 0.f;
#pragma unroll
  for (int i = 0; i < 8; ++i) s += v[i];
#pragma unroll
  for (int off = 32; off; off >>= 1) s += __shfl_xor(s, off);
  float mu = s * (1.0f / 512.0f);
  float q = 0.f;
#pragma unroll
  for (int i = 0; i < 8; ++i) { float d = v[i] - mu; q += d * d; }
#pragma unroll
  for (int off = 32; off; off >>= 1) q += __shfl_xor(q, off);
  float rstd = rsqrtf(q * (1.0f / 512.0f) + 1e-5f);
  us8 oln, oraw;
#pragma unroll
  for (int i = 0; i < 8; ++i) {
    int col = lane * 8 + i;
    oln[i] = bf16u((v[i] - mu) * rstd * g[col] + b[col]);
    oraw[i] = bf16u(v[i]);
  }
  size_t off8 = (size_t)row * kD + lane * 8;
  *(us8*)(outLN + off8) = oln;
  *(us8*)(outRaw + off8) = oraw;
}

// ---- LN with bf16 input -> bf16 out ----
__global__ __launch_bounds__(256) void ln_b16_kernel(const unsigned short* __restrict__ in,
                                                     const float* __restrict__ g,
                                                     const float* __restrict__ b,
                                                     unsigned short* __restrict__ outb,
                                                     int nrows) {
  int wave = threadIdx.x >> 6, lane = threadIdx.x & 63;
  int row = blockIdx.x * 4 + wave;
  if (row >= nrows) return;
  us8 iv = *(const us8*)(in + (size_t)row * kD + lane * 8);
  float v[8];
#pragma unroll
  for (int i = 0; i < 8; ++i) v[i] = b2f(iv[i]);
  float s = 0.f;
#pragma unroll
  for (int i = 0; i < 8; ++i) s += v[i];
#pragma unroll
  for (int off = 32; off; off >>= 1) s += __shfl_xor(s, off);
  float mu = s * (1.0f / 512.0f);
  float q = 0.f;
#pragma unroll
  for (int i = 0; i < 8; ++i) { float d = v[i] - mu; q += d * d; }
#pragma unroll
  for (int off = 32; off; off >>= 1) q += __shfl_xor(q, off);
  float rstd = rsqrtf(q * (1.0f / 512.0f) + 1e-5f);
  us8 o;
#pragma unroll
  for (int i = 0; i < 8; ++i) {
    int col = lane * 8 + i;
    o[i] = bf16u((v[i] - mu) * rstd * g[col] + b[col]);
  }
  *(us8*)(outb + (size_t)row * kD + lane * 8) = o;
}

// ============ MFMA GEMM, B^T input: C[M][N] = A[M][K] @ Bt[N][K]^T ==========
// 128 x TN tile, 256 threads (4 waves), BK=32, global_load_lds width 16.
// EPI: 0 = fp32 out, 1 = bf16 out, 2 = bias+relu+bf16, 3 = bias+bf16.
template <int TN, int EPI>
__global__ __launch_bounds__(256) void mfma_gemm_bt(
    const unsigned short* __restrict__ A, const unsigned short* __restrict__ Bt,
    int K, const float* __restrict__ bias, void* __restrict__ Cv, int N) {
  constexpr int MI = (TN == 128) ? 4 : 2;
  constexpr int NJ = 4;
  constexpr int BCH = TN * 64 / 1024;
  __shared__ __align__(16) unsigned short As[128 * kBK];
  __shared__ __align__(16) unsigned short Bs[TN * kBK];
  const int tid = threadIdx.x;
  const int lane = tid & 63, wv = tid >> 6;
  const int ml = lane & 15, qd = lane >> 4;
  const int m0 = blockIdx.y * 128, n0 = blockIdx.x * TN;
  const int mw0 = (TN == 128) ? (wv >> 1) * 64 : wv * 32;
  const int nw0 = (TN == 128) ? (wv & 1) * 64 : 0;
  const size_t ldA = (size_t)K * 2, ldB = (size_t)K * 2;
  const char* Ab = (const char*)A + (size_t)m0 * ldA;
  const char* Bb = (const char*)Bt + (size_t)n0 * ldB;
  f32x4 acc[MI][NJ];
#pragma unroll
  for (int i = 0; i < MI; ++i)
#pragma unroll
    for (int j = 0; j < NJ; ++j) acc[i][j] = (f32x4)0.f;
  for (int k0 = 0; k0 < K; k0 += kBK) {
#pragma unroll
    for (int c = wv; c < 8; c += 4) {
      int fb = c * 1024 + lane * 16;
      gl_lds16(Ab + (size_t)(fb >> 6) * ldA + (fb & 63) + (size_t)k0 * 2,
               (char*)As + c * 1024);
    }
#pragma unroll
    for (int c = wv; c < BCH; c += 4) {
      int fb = c * 1024 + lane * 16;
      gl_lds16(Bb + (size_t)(fb >> 6) * ldB + (fb & 63) + (size_t)k0 * 2,
               (char*)Bs + c * 1024);
    }
    __syncthreads();
    bf16x8 af[MI], bfr[NJ];
#pragma unroll
    for (int i = 0; i < MI; ++i)
      af[i] = *(const bf16x8*)(As + (mw0 + i * 16 + ml) * kBK + qd * 8);
#pragma unroll
    for (int j = 0; j < NJ; ++j)
      bfr[j] = *(const bf16x8*)(Bs + (nw0 + j * 16 + ml) * kBK + qd * 8);
#pragma unroll
    for (int i = 0; i < MI; ++i)
#pragma unroll
      for (int j = 0; j < NJ; ++j)
        acc[i][j] = __builtin_amdgcn_mfma_f32_16x16x32_bf16(af[i], bfr[j], acc[i][j], 0, 0, 0);
    __syncthreads();
  }
#pragma unroll
  for (int i = 0; i < MI; ++i)
#pragma unroll
    for (int j = 0; j < NJ; ++j)
#pragma unroll
      for (int r = 0; r < 4; ++r) {
        int m = m0 + mw0 + i * 16 + qd * 4 + r;
        int n = n0 + nw0 + j * 16 + ml;
        float val = acc[i][j][r];
        if (EPI >= 2) val += bias[n];
        if (EPI == 2) val = fmaxf(val, 0.f);
        size_t idx = (size_t)m * N + n;
        if (EPI == 0) ((float*)Cv)[idx] = val;
        else ((unsigned short*)Cv)[idx] = bf16u(val);
      }
}

// ====== gate r: acc = Y@W0t^T + X@W1t^T ; RX = bf16(sigmoid(acc+b0+b1)*x) ==
__global__ __launch_bounds__(256) void mfma_gate_r(
    const unsigned short* __restrict__ Yb, const unsigned short* __restrict__ Xb,
    const unsigned short* __restrict__ Wt, const float* __restrict__ gb,
    unsigned short* __restrict__ RX) {
  __shared__ __align__(16) unsigned short As[128 * kBK];
  __shared__ __align__(16) unsigned short Bs[128 * kBK];
  const int tid = threadIdx.x;
  const int lane = tid & 63, wv = tid >> 6;
  const int ml = lane & 15, qd = lane >> 4;
  const int m0 = blockIdx.y * 128, n0 = blockIdx.x * 128;
  const int mw0 = (wv >> 1) * 64, nw0 = (wv & 1) * 64;
  const size_t ld = (size_t)kD * 2;
  f32x4 acc[4][4];
#pragma unroll
  for (int i = 0; i < 4; ++i)
#pragma unroll
    for (int j = 0; j < 4; ++j) acc[i][j] = (f32x4)0.f;
  for (int p = 0; p < 2; ++p) {
    const char* Ab = (const char*)(p ? Xb : Yb) + (size_t)m0 * ld;
    const char* Bb = (const char*)(Wt + (size_t)p * kD * kD) + (size_t)n0 * ld;
    for (int k0 = 0; k0 < kD; k0 += kBK) {
#pragma unroll
      for (int c = wv; c < 8; c += 4) {
        int fb = c * 1024 + lane * 16;
        gl_lds16(Ab + (size_t)(fb >> 6) * ld + (fb & 63) + (size_t)k0 * 2,
                 (char*)As + c * 1024);
        gl_lds16(Bb + (size_t)(fb >> 6) * ld + (fb & 63) + (size_t)k0 * 2,
                 (char*)Bs + c * 1024);
      }
      __syncthreads();
      bf16x8 af[4], bfr[4];
#pragma unroll
      for (int i = 0; i < 4; ++i)
        af[i] = *(const bf16x8*)(As + (mw0 + i * 16 + ml) * kBK + qd * 8);
#pragma unroll
      for (int j = 0; j < 4; ++j)
        bfr[j] = *(const bf16x8*)(Bs + (nw0 + j * 16 + ml) * kBK + qd * 8);
#pragma unroll
      for (int i = 0; i < 4; ++i)
#pragma unroll
        for (int j = 0; j < 4; ++j)
          acc[i][j] = __builtin_amdgcn_mfma_f32_16x16x32_bf16(af[i], bfr[j], acc[i][j], 0, 0, 0);
      __syncthreads();
    }
  }
#pragma unroll
  for (int i = 0; i < 4; ++i)
#pragma unroll
    for (int j = 0; j < 4; ++j)
#pragma unroll
      for (int r = 0; r < 4; ++r) {
        int m = m0 + mw0 + i * 16 + qd * 4 + r;
        int n = n0 + nw0 + j * 16 + ml;
        float rg = sigmoidf_(acc[i][j][r] + gb[n] + gb[kD + n]);
        size_t idx = (size_t)m * kD + n;
        RX[idx] = bf16u(rg * b2f(Xb[idx]));
      }
}

// ====== gate h (3 passes, dual-B on pass0):
// accH = Y@W4 + RX@W5 ; accZ = Y@W2 + X@W3
// pass0: A=Y, B0=W4 (accH), B1=W2 (accZ); pass1: A=RX -> W5 (accH);
// pass2: A=X -> W3 (accZ).
// out = (1-z)*x + z*tanh(accH+b4+b5), z = sigmoid(accZ+b2+b3-BG), x bf16.
// POOL=false: OUTb bf16. POOL=true: atomic mean-pool into TS.
template <bool POOL>
__global__ __launch_bounds__(256) void mfma_gate_h3(
    const unsigned short* __restrict__ Yb, const unsigned short* __restrict__ RXb,
    const unsigned short* __restrict__ Xb, const unsigned short* __restrict__ Wt,
    const float* __restrict__ gb, unsigned short* __restrict__ OUTb,
    float* __restrict__ TS, int rowoff) {
  __shared__ __align__(16) unsigned short As[128 * kBK];
  __shared__ __align__(16) unsigned short Bs0[128 * kBK];
  __shared__ __align__(16) unsigned short Bs1[128 * kBK];
  const int tid = threadIdx.x;
  const int lane = tid & 63, wv = tid >> 6;
  const int ml = lane & 15, qd = lane >> 4;
  const int m0 = blockIdx.y * 128, n0 = blockIdx.x * 128;
  const int mw0 = (wv >> 1) * 64, nw0 = (wv & 1) * 64;
  const size_t ld = (size_t)kD * 2;
  const size_t DD = (size_t)kD * kD;
  f32x4 accH[4][4], accZ[4][4];
#pragma unroll
  for (int i = 0; i < 4; ++i)
#pragma unroll
    for (int j = 0; j < 4; ++j) { accH[i][j] = (f32x4)0.f; accZ[i][j] = (f32x4)0.f; }

  // ---- pass 0: A = Y, dual B (W4 -> accH, W2 -> accZ) ----
  {
    const char* Ab = (const char*)Yb + (size_t)m0 * ld;
    const char* B0b = (const char*)(Wt + 4 * DD) + (size_t)n0 * ld;
    const char* B1b = (const char*)(Wt + 2 * DD) + (size_t)n0 * ld;
    for (int k0 = 0; k0 < kD; k0 += kBK) {
#pragma unroll
      for (int c = wv; c < 8; c += 4) {
        int fb = c * 1024 + lane * 16;
        size_t go = (size_t)(fb >> 6) * ld + (fb & 63) + (size_t)k0 * 2;
        gl_lds16(Ab + go, (char*)As + c * 1024);
        gl_lds16(B0b + go, (char*)Bs0 + c * 1024);
        gl_lds16(B1b + go, (char*)Bs1 + c * 1024);
      }
      __syncthreads();
      bf16x8 af[4], b0[4], b1[4];
#pragma unroll
      for (int i = 0; i < 4; ++i)
        af[i] = *(const bf16x8*)(As + (mw0 + i * 16 + ml) * kBK + qd * 8);
#pragma unroll
      for (int j = 0; j < 4; ++j) {
        b0[j] = *(const bf16x8*)(Bs0 + (nw0 + j * 16 + ml) * kBK + qd * 8);
        b1[j] = *(const bf16x8*)(Bs1 + (nw0 + j * 16 + ml) * kBK + qd * 8);
      }
#pragma unroll
      for (int i = 0; i < 4; ++i)
#pragma unroll
        for (int j = 0; j < 4; ++j) {
          accH[i][j] = __builtin_amdgcn_mfma_f32_16x16x32_bf16(af[i], b0[j], accH[i][j], 0, 0, 0);
          accZ[i][j] = __builtin_amdgcn_mfma_f32_16x16x32_bf16(af[i], b1[j], accZ[i][j], 0, 0, 0);
        }
      __syncthreads();
    }
  }
  // ---- pass 1 (A=RX -> W5, accH) and pass 2 (A=X -> W3, accZ) ----
#pragma unroll
  for (int p = 0; p < 2; ++p) {
    const char* Ab = (const char*)(p ? Xb : RXb) + (size_t)m0 * ld;
    const char* Bb = (const char*)(Wt + (p ? 3 : 5) * DD) + (size_t)n0 * ld;
    for (int k0 = 0; k0 < kD; k0 += kBK) {
#pragma unroll
      for (int c = wv; c < 8; c += 4) {
        int fb = c * 1024 + lane * 16;
        size_t go = (size_t)(fb >> 6) * ld + (fb & 63) + (size_t)k0 * 2;
        gl_lds16(Ab + go, (char*)As + c * 1024);
        gl_lds16(Bb + go, (char*)Bs0 + c * 1024);
      }
      __syncthreads();
      bf16x8 af[4], bfr[4];
#pragma unroll
      for (int i = 0; i < 4; ++i)
        af[i] = *(const bf16x8*)(As + (mw0 + i * 16 + ml) * kBK + qd * 8);
#pragma unroll
      for (int j = 0; j < 4; ++j)
        bfr[j] = *(const bf16x8*)(Bs0 + (nw0 + j * 16 + ml) * kBK + qd * 8);
#pragma unroll
      for (int i = 0; i < 4; ++i)
#pragma unroll
        for (int j = 0; j < 4; ++j) {
          if (p == 0)
            accH[i][j] = __builtin_amdgcn_mfma_f32_16x16x32_bf16(af[i], bfr[j], accH[i][j], 0, 0, 0);
          else
            accZ[i][j] = __builtin_amdgcn_mfma_f32_16x16x32_bf16(af[i], bfr[j], accZ[i][j], 0, 0, 0);
        }
      __syncthreads();
    }
  }
#pragma unroll
  for (int i = 0; i < 4; ++i)
#pragma unroll
    for (int j = 0; j < 4; ++j)
#pragma unroll
      for (int r = 0; r < 4; ++r) {
        int m = m0 + mw0 + i * 16 + qd * 4 + r;
        int n = n0 + nw0 + j * 16 + ml;
        float z = sigmoidf_(accZ[i][j][r] + gb[2 * kD + n] + gb[3 * kD + n] - kBG);
        float hc = tanhf(accH[i][j][r] + gb[4 * kD + n] + gb[5 * kD + n]);
        size_t idx = (size_t)m * kD + n;
        float val = (1.0f - z) * b2f(Xb[idx]) + z * hc;
        if (POOL) {
          int b = (rowoff + m) & (kB - 1);
          atomicAdd(TS + (size_t)b * kD + n, val * (1.0f / kT));
        } else {
          OUTb[idx] = bf16u(val);
        }
      }
}

// -------- Positional embedding projection ----------
__global__ __launch_bounds__(64) void posp_kernel(const float* __restrict__ Wp,
                                                  float* __restrict__ P) {
  __shared__ float emb[512];
  int jj = blockIdx.x;
  int t = threadIdx.x;
  float pos = (float)(kJ - 1 - jj);
#pragma unroll
  for (int r = 0; r < 8; ++r) {
    int d = t + r * 64;
    int i = (d < 256) ? d : d - 256;
    float invf = expf(-((float)(2 * i) * (1.0f / 512.0f)) * 9.210340371976184f);
    float si = pos * invf;
    emb[d] = (d < 256) ? sinf(si) : cosf(si);
  }
  __syncthreads();
  float acc = 0.f;
  for (int d = 0; d < 512; ++d) acc = fmaf(emb[d], Wp[d * 64 + t], acc);
  P[jj * 64 + t] = acc;
}

// -------- Attention (fp32 math), AV out as bf16 ----------
__global__ __launch_bounds__(128) void attn_kernel(
    const float* __restrict__ Q, const float* __restrict__ KV,
    const float* __restrict__ P, const float* __restrict__ U,
    const float* __restrict__ V, unsigned short* __restrict__ AV) {
  __shared__ float ks[kJ][32];
  __shared__ float vs[kJ][32];
  __shared__ float ps[32][kJ + 2];
  const int b = blockIdx.x, h = blockIdx.y;
  const int tid = threadIdx.x;
  for (int idx = tid; idx < kJ * 8; idx += 128) {
    int j = idx >> 3, seg = idx & 7;
    const float* src = KV + ((size_t)(j * kB + b)) * 128 + h * 32 + seg * 4;
    float4 kq = *(const float4*)src;
    float4 vq = *(const float4*)(src + 64);
    *(float4*)&ks[j][seg * 4] = kq;
    *(float4*)&vs[j][seg * 4] = vq;
  }
  for (int idx = tid; idx < kJ * 8; idx += 128) {
    int j = idx >> 3, seg = idx & 7;
    float4 pq = *(const float4*)(P + j * 64 + h * 32 + seg * 4);
    ps[seg * 4 + 0][j] = pq.x;
    ps[seg * 4 + 1][j] = pq.y;
    ps[seg * 4 + 2][j] = pq.z;
    ps[seg * 4 + 3][j] = pq.w;
  }
  __syncthreads();
  const int i = tid;
  float qu[32], qv[32];
  const float* qp = Q + ((size_t)(i * kB + b)) * 64 + h * 32;
#pragma unroll
  for (int d = 0; d < 32; ++d) {
    float qd = qp[d];
    qu[d] = qd + U[h * 32 + d];
    qv[d] = qd + V[h * 32 + d];
  }
  float m = -INFINITY, l = 0.f, acc[32] = {};
  const float scale = 0.17677669529663687f;
  for (int j = 0; j <= i + kM; ++j) {
    float s = 0.f;
#pragma unroll
    for (int d = 0; d < 32; d += 4) {
      float4 k4 = *(const float4*)&ks[j][d];
      s = fmaf(qu[d + 0], k4.x, s);
      s = fmaf(qu[d + 1], k4.y, s);
      s = fmaf(qu[d + 2], k4.z, s);
      s = fmaf(qu[d + 3], k4.w, s);
    }
    int jj = j + (kT - 1) - i;
#pragma unroll
    for (int d = 0; d < 32; ++d) s = fmaf(qv[d], ps[d][jj], s);
    float ls = s * scale;
    float nm = fmaxf(m, ls);
    float w = __expf(ls - nm);
    float f = __expf(m - nm);
    l = l * f + w;
#pragma unroll
    for (int d = 0; d < 32; d += 4) {
      float4 v4 = *(const float4*)&vs[j][d];
      acc[d + 0] = fmaf(acc[d + 0], f, w * v4.x);
      acc[d + 1] = fmaf(acc[d + 1], f, w * v4.y);
      acc[d + 2] = fmaf(acc[d + 2], f, w * v4.z);
      acc[d + 3] = fmaf(acc[d + 3], f, w * v4.w);
    }
    m = nm;
  }
  float inv = 1.0f / l;
  unsigned short* o = AV + ((size_t)(i * kB + b)) * 64 + h * 32;
#pragma unroll
  for (int d = 0; d < 32; ++d) o[d] = bf16u(acc[d] * inv);
}

// -------- fp32 fallback GEMM for the small critic head --------
template <int ACTF, bool DUAL>
__global__ __launch_bounds__(256) void gemm_kernel(
    const float* __restrict__ A1, const float* __restrict__ Bm1, int K1,
    const float* __restrict__ A2, const float* __restrict__ Bm2, int K2,
    const float* __restrict__ bias, float* __restrict__ C, int Mrows, int N) {
  __shared__ float As[16][68];
  __shared__ float Bs[16][68];
  const int tid = threadIdx.x;
  const int tx = tid & 15, ty = tid >> 4;
  const int m0 = blockIdx.y * 64, n0 = blockIdx.x * 64;
  const int ar = tid >> 2, aseg = tid & 3;
  float acc[4][4] = {};
#pragma unroll
  for (int pass = 0; pass < (DUAL ? 2 : 1); ++pass) {
    const float* A = (DUAL && pass) ? A2 : A1;
    const float* Bm = (DUAL && pass) ? Bm2 : Bm1;
    const int K = (DUAL && pass) ? K2 : K1;
    for (int k0 = 0; k0 < K; k0 += 16) {
      {
        int row = m0 + ar;
        int kb = k0 + aseg * 4;
        float x0 = 0.f, x1 = 0.f, x2 = 0.f, x3 = 0.f;
        if (row < Mrows) {
          const float* ap = A + (size_t)row * K + kb;
          if (kb + 3 < K) {
            float4 t = *(const float4*)ap;
            x0 = t.x; x1 = t.y; x2 = t.z; x3 = t.w;
          } else {
            if (kb + 0 < K) x0 = ap[0];
            if (kb + 1 < K) x1 = ap[1];
            if (kb + 2 < K) x2 = ap[2];
          }
        }
        As[aseg * 4 + 0][ar] = x0;
        As[aseg * 4 + 1][ar] = x1;
        As[aseg * 4 + 2][ar] = x2;
        As[aseg * 4 + 3][ar] = x3;
      }
      {
        int krow = k0 + ty;
        int nb = n0 + tx * 4;
        float y0 = 0.f, y1 = 0.f, y2 = 0.f, y3 = 0.f;
        if (krow < K) {
          const float* bp = Bm + (size_t)krow * N + nb;
          if (nb + 3 < N) {
            float4 t = *(const float4*)bp;
            y0 = t.x; y1 = t.y; y2 = t.z; y3 = t.w;
          } else {
            if (nb + 0 < N) y0 = bp[0];
            if (nb + 1 < N) y1 = bp[1];
            if (nb + 2 < N) y2 = bp[2];
          }
        }
        *(float4*)&Bs[ty][tx * 4] = make_float4(y0, y1, y2, y3);
      }
      __syncthreads();
#pragma unroll
      for (int kk = 0; kk < 16; ++kk) {
        float a[4], bb[4];
        *(float4*)a = *(const float4*)&As[kk][ty * 4];
        *(float4*)bb = *(const float4*)&Bs[kk][tx * 4];
#pragma unroll
        for (int i = 0; i < 4; ++i)
#pragma unroll
          for (int j = 0; j < 4; ++j) acc[i][j] = fmaf(a[i], bb[j], acc[i][j]);
      }
      __syncthreads();
    }
  }
#pragma unroll
  for (int i = 0; i < 4; ++i) {
    int m = m0 + ty * 4 + i;
    if (m >= Mrows) continue;
#pragma unroll
    for (int j = 0; j < 4; ++j) {
      int n = n0 + tx * 4 + j;
      if (n >= N) continue;
      float val = acc[i][j];
      if (bias) val += bias[n];
      if (ACTF == 1) val = fmaxf(val, 0.f);
      C[(size_t)m * N + n] = val;
    }
  }
}

}  // namespace

extern "C" void kernel_launch(void* const* d_in, const int* in_sizes, int n_in,
                              void* d_out, int out_size, void* d_ws, size_t ws_size,
                              hipStream_t stream) {
  (void)in_sizes; (void)n_in; (void)out_size;
  const float* aug    = (const float*)d_in[0];
  const float* action = (const float*)d_in[1];
  const float* memory = (const float*)d_in[2];
  const float* W_q    = (const float*)d_in[3];
  const float* W_kv   = (const float*)d_in[4];
  const float* W_p    = (const float*)d_in[5];
  const float* W_out  = (const float*)d_in[6];
  const float* u      = (const float*)d_in[7];
  const float* v      = (const float*)d_in[8];
  const float* ln1_g  = (const float*)d_in[9];
  const float* ln1_b  = (const float*)d_in[10];
  const float* ln2_g  = (const float*)d_in[11];
  const float* ln2_b  = (const float*)d_in[12];
  const float* ff_W1  = (const float*)d_in[13];
  const float* ff_b1  = (const float*)d_in[14];
  const float* ff_W2  = (const float*)d_in[15];
  const float* ff_b2  = (const float*)d_in[16];
  const float* g1_W   = (const float*)d_in[17];
  const float* g1_b   = (const float*)d_in[18];
  const float* g2_W   = (const float*)d_in[19];
  const float* g2_b   = (const float*)d_in[20];
  const float* d1_W   = (const float*)d_in[21];
  const float* d1_b   = (const float*)d_in[22];
  const float* d2_W   = (const float*)d_in[23];
  const float* d2_b   = (const float*)d_in[24];
  const float* d3_W   = (const float*)d_in[25];
  const float* d3_b   = (const float*)d_in[26];
  const float* d4_W   = (const float*)d_in[27];
  const float* d4_b   = (const float*)d_in[28];
  float* out = (float*)d_out;

  // ---------------- workspace carve ----------------
  char* base = (char*)d_ws;
  auto alloc = [&](size_t bytes) -> char* {
    char* p = base;
    base += (bytes + 255) & ~(size_t)255;
    return p;
  };
  unsigned short* Wqt  = (unsigned short*)alloc((size_t)64 * 512 * 2);
  unsigned short* Wkvt = (unsigned short*)alloc((size_t)128 * 512 * 2);
  unsigned short* Wot  = (unsigned short*)alloc((size_t)512 * 64 * 2);
  unsigned short* Wf1t = (unsigned short*)alloc((size_t)64 * 512 * 2);
  unsigned short* Wf2t = (unsigned short*)alloc((size_t)512 * 64 * 2);
  unsigned short* G1t  = (unsigned short*)alloc((size_t)6 * 512 * 512 * 2);
  unsigned short* G2t  = (unsigned short*)alloc((size_t)6 * 512 * 512 * 2);
  unsigned short* Memb = (unsigned short*)alloc((size_t)3072 * 512 * 2);
  float* KVb = (float*)alloc((size_t)kJ * kB * 128 * 4);
  float* Qb  = (float*)alloc((size_t)kTB * 64 * 4);
  unsigned short* AVb = (unsigned short*)alloc((size_t)kTB * 64 * 2);
  unsigned short* Xb  = (unsigned short*)alloc((size_t)kTB * kD * 2);  // raw aug bf16
  float* Pb  = (float*)alloc((size_t)kJ * 64 * 4);
  float* TSb = (float*)alloc((size_t)kB * kD * 4);
  float* H1b = (float*)alloc((size_t)kB * 1024 * 4);
  float* H2b = (float*)alloc((size_t)kB * 512 * 4);
  float* H3b = (float*)alloc((size_t)kB * 320 * 4);
  size_t fixedBytes = (size_t)(base - (char*)d_ws);
  const size_t ln1Bytes = (size_t)kTB * kD * 2;  // L1b overlaps chunk region
  int nch = 1;
  while (nch < 32) {
    size_t chunkBytes = (size_t)(kTB / nch) * 4224 + 4096;
    size_t reuse = chunkBytes > ln1Bytes ? chunkBytes : ln1Bytes;
    if (fixedBytes + reuse <= ws_size) break;
    nch <<= 1;
  }
  const int CR = kTB / nch;
  char* R = base;
  unsigned short* L1b = (unsigned short*)R;  // ln1(aug) bf16 (dead before chunks)
  char* rp = R;
  auto ralloc = [&](size_t bytes) -> char* {
    char* p = rp;
    rp += (bytes + 255) & ~(size_t)255;
    return p;
  };
  unsigned short* Ycb   = (unsigned short*)ralloc((size_t)CR * 512 * 2);
  unsigned short* RXcb  = (unsigned short*)ralloc((size_t)CR * 512 * 2);
  unsigned short* SRCcb = (unsigned short*)ralloc((size_t)CR * 512 * 2);
  unsigned short* LN2cb = (unsigned short*)ralloc((size_t)CR * 512 * 2);
  unsigned short* F1cb  = (unsigned short*)ralloc((size_t)CR * 64 * 2);

  const float* np = nullptr;

  // -------- prep --------
  hipMemsetAsync(TSb, 0, (size_t)kB * kD * sizeof(float), stream);
  transp_kernel<<<dim3(2, 16, 1), 256, 0, stream>>>(W_q, Wqt, 512, 64);
  transp_kernel<<<dim3(4, 16, 1), 256, 0, stream>>>(W_kv, Wkvt, 512, 128);
  transp_kernel<<<dim3(16, 2, 1), 256, 0, stream>>>(W_out, Wot, 64, 512);
  transp_kernel<<<dim3(2, 16, 1), 256, 0, stream>>>(ff_W1, Wf1t, 512, 64);
  transp_kernel<<<dim3(16, 2, 1), 256, 0, stream>>>(ff_W2, Wf2t, 64, 512);
  transp_kernel<<<dim3(16, 16, 6), 256, 0, stream>>>(g1_W, G1t, 512, 512);
  transp_kernel<<<dim3(16, 16, 6), 256, 0, stream>>>(g2_W, G2t, 512, 512);
  conv_bf16_kernel<<<(3072 * 512 / 8 + 255) / 256, 256, 0, stream>>>(
      memory, Memb, (size_t)3072 * 512);
  // ln1(aug) -> L1b bf16 and raw aug -> Xb bf16 (one fp32 read)
  ln1_dual_kernel<<<kTB / 4, 256, 0, stream>>>(aug, ln1_g, ln1_b, L1b, Xb, kTB);
  // kv = [memory; ln1] @ W_kv  (fp32 out)
  mfma_gemm_bt<128, 0><<<dim3(1, 3072 / 128), 256, 0, stream>>>(
      Memb, Wkvt, 512, np, KVb, 128);
  mfma_gemm_bt<128, 0><<<dim3(1, kTB / 128), 256, 0, stream>>>(
      L1b, Wkvt, 512, np, KVb + (size_t)3072 * 128, 128);
  // q = ln1 @ W_q (fp32 out)
  mfma_gemm_bt<64, 0><<<dim3(1, kTB / 128), 256, 0, stream>>>(
      L1b, Wqt, 512, np, Qb, 64);
  posp_kernel<<<kJ, 64, 0, stream>>>(W_p, Pb);
  attn_kernel<<<dim3(kB, kH), 128, 0, stream>>>(Qb, KVb, Pb, u, v, AVb);

  for (int c = 0; c < nch; ++c) {
    const int R0 = c * CR;
    const unsigned short* Xc = Xb + (size_t)R0 * kD;
    // y1 = av @ W_out (bf16 out)
    mfma_gemm_bt<128, 1><<<dim3(4, CR / 128), 256, 0, stream>>>(
        AVb + (size_t)R0 * 64, Wot, 64, np, Ycb, 512);
    // gate1
    mfma_gate_r<<<dim3(4, CR / 128), 256, 0, stream>>>(Ycb, Xc, G1t, g1_b, RXcb);
    mfma_gate_h3<false><<<dim3(4, CR / 128), 256, 0, stream>>>(
        Ycb, RXcb, Xc, G1t, g1_b, SRCcb, nullptr, R0);
    // ln2 (bf16 in/out)
    ln_b16_kernel<<<CR / 4, 256, 0, stream>>>(SRCcb, ln2_g, ln2_b, LN2cb, CR);
    // ff1 = relu(ln2 @ ff_W1 + b1) (bf16 out)
    mfma_gemm_bt<64, 2><<<dim3(1, CR / 128), 256, 0, stream>>>(
        LN2cb, Wf1t, 512, ff_b1, F1cb, 64);
    // y2 = ff1 @ ff_W2 + b2 (bf16 out)
    mfma_gemm_bt<128, 3><<<dim3(4, CR / 128), 256, 0, stream>>>(
        F1cb, Wf2t, 64, ff_b2, Ycb, 512);
    // gate2 + fused mean-pool
    mfma_gate_r<<<dim3(4, CR / 128), 256, 0, stream>>>(Ycb, SRCcb, G2t, g2_b, RXcb);
    mfma_gate_h3<true><<<dim3(4, CR / 128), 256, 0, stream>>>(
        Ycb, RXcb, SRCcb, G2t, g2_b, nullptr, TSb, R0);
  }

  // critic head (fp32)
  gemm_kernel<1, false><<<dim3(16, kB / 64), 256, 0, stream>>>(
      TSb, d1_W, 512, np, np, 0, d1_b, H1b, kB, 1024);
  gemm_kernel<1, true><<<dim3(8, kB / 64), 256, 0, stream>>>(
      H1b, d2_W, 1024, action, d2_W + (size_t)1024 * 512, 64, d2_b, H2b, kB, 512);
  gemm_kernel<1, false><<<dim3(5, kB / 64), 256, 0, stream>>>(
      H2b, d3_W, 512, np, np, 0, d3_b, H3b, kB, 300);
  gemm_kernel<1, false><<<dim3(1, kB / 64), 256, 0, stream>>>(
      H3b, d4_W, 300, np, np, 0, d4_b, out, kB, 1);
}

// Round 5
// 1833.938 us; speedup vs baseline: 1.1624x; 1.1624x over previous
//
#include <hip/hip_runtime.h>
#include <math.h>

namespace {

constexpr int kT = 128, kB = 512, kD = 512, kM = 6, kH = 2;
constexpr int kJ = kT + kM;          // 134
constexpr float kBG = 0.1f;
constexpr int kTB = kT * kB;         // 65536 rows
constexpr int kBK = 32;              // K-tile for MFMA kernels

typedef __attribute__((ext_vector_type(8))) short bf16x8;
typedef __attribute__((ext_vector_type(4))) float f32x4;
typedef __attribute__((ext_vector_type(8))) unsigned short us8;
typedef __attribute__((ext_vector_type(4))) unsigned short us4;

__device__ __forceinline__ float sigmoidf_(float x) {
  return 1.0f / (1.0f + __expf(-x));
}

__device__ __forceinline__ unsigned short bf16u(float f) {
  union { float f; unsigned u; } c; c.f = f;
  unsigned r = c.u + 0x7fffu + ((c.u >> 16) & 1u);
  return (unsigned short)(r >> 16);
}

__device__ __forceinline__ float b2f(unsigned short u) {
  union { unsigned u; float f; } c; c.u = (unsigned)u << 16;
  return c.f;
}

__device__ __forceinline__ void gl_lds16(const void* g, void* l) {
  __builtin_amdgcn_global_load_lds(
      (const __attribute__((address_space(1))) unsigned int*)g,
      (__attribute__((address_space(3))) unsigned int*)l, 16, 0, 0);
}

// ---- transpose + cast: W fp32 [K][N] -> Wt bf16 [N][K]; dims mult of 32 ----
__global__ __launch_bounds__(256) void transp_kernel(const float* __restrict__ W,
                                                     unsigned short* __restrict__ Wt,
                                                     int K, int N) {
  __shared__ float t[32][33];
  const int n0 = blockIdx.x * 32, k0 = blockIdx.y * 32;
  const float* Wb = W + (size_t)blockIdx.z * K * N;
  unsigned short* Wtb = Wt + (size_t)blockIdx.z * K * N;
  int tx = threadIdx.x & 31, ty = threadIdx.x >> 5;  // 32 x 8
#pragma unroll
  for (int r = 0; r < 32; r += 8)
    t[ty + r][tx] = Wb[(size_t)(k0 + ty + r) * N + n0 + tx];
  __syncthreads();
#pragma unroll
  for (int r = 0; r < 32; r += 8)
    Wtb[(size_t)(n0 + ty + r) * K + k0 + tx] = bf16u(t[tx][ty + r]);
}

// ---- fp32 -> bf16 elementwise (n multiple of 8) ----
__global__ __launch_bounds__(256) void conv_bf16_kernel(const float* __restrict__ in,
                                                        unsigned short* __restrict__ outb,
                                                        size_t n) {
  size_t idx = ((size_t)blockIdx.x * 256 + threadIdx.x) * 8;
  if (idx >= n) return;
  float4 a = *(const float4*)(in + idx);
  float4 c = *(const float4*)(in + idx + 4);
  us8 o;
  o[0] = bf16u(a.x); o[1] = bf16u(a.y); o[2] = bf16u(a.z); o[3] = bf16u(a.w);
  o[4] = bf16u(c.x); o[5] = bf16u(c.y); o[6] = bf16u(c.z); o[7] = bf16u(c.w);
  *(us8*)(outb + idx) = o;
}

// ---- LN1 dual-output: LN(x) -> bf16 AND raw x -> bf16, one fp32 read ----
__global__ __launch_bounds__(256) void ln1_dual_kernel(const float* __restrict__ in,
                                                       const float* __restrict__ g,
                                                       const float* __restrict__ b,
                                                       unsigned short* __restrict__ outLN,
                                                       unsigned short* __restrict__ outRaw,
                                                       int nrows) {
  int wave = threadIdx.x >> 6, lane = threadIdx.x & 63;
  int row = blockIdx.x * 4 + wave;
  if (row >= nrows) return;
  const float* p = in + (size_t)row * kD + lane * 8;
  float4 a = *(const float4*)p;
  float4 c = *(const float4*)(p + 4);
  float v[8] = {a.x, a.y, a.z, a.w, c.x, c.y, c.z, c.w};
  float s = 0.f;
#pragma unroll
  for (int i = 0; i < 8; ++i) s += v[i];
#pragma unroll
  for (int off = 32; off; off >>= 1) s += __shfl_xor(s, off);
  float mu = s * (1.0f / 512.0f);
  float q = 0.f;
#pragma unroll
  for (int i = 0; i < 8; ++i) { float d = v[i] - mu; q += d * d; }
#pragma unroll
  for (int off = 32; off; off >>= 1) q += __shfl_xor(q, off);
  float rstd = rsqrtf(q * (1.0f / 512.0f) + 1e-5f);
  us8 oln, oraw;
#pragma unroll
  for (int i = 0; i < 8; ++i) {
    int col = lane * 8 + i;
    oln[i] = bf16u((v[i] - mu) * rstd * g[col] + b[col]);
    oraw[i] = bf16u(v[i]);
  }
  size_t off8 = (size_t)row * kD + lane * 8;
  *(us8*)(outLN + off8) = oln;
  *(us8*)(outRaw + off8) = oraw;
}

// ---- LN with bf16 input -> bf16 out ----
__global__ __launch_bounds__(256) void ln_b16_kernel(const unsigned short* __restrict__ in,
                                                     const float* __restrict__ g,
                                                     const float* __restrict__ b,
                                                     unsigned short* __restrict__ outb,
                                                     int nrows) {
  int wave = threadIdx.x >> 6, lane = threadIdx.x & 63;
  int row = blockIdx.x * 4 + wave;
  if (row >= nrows) return;
  us8 iv = *(const us8*)(in + (size_t)row * kD + lane * 8);
  float v[8];
#pragma unroll
  for (int i = 0; i < 8; ++i) v[i] = b2f(iv[i]);
  float s = 0.f;
#pragma unroll
  for (int i = 0; i < 8; ++i) s += v[i];
#pragma unroll
  for (int off = 32; off; off >>= 1) s += __shfl_xor(s, off);
  float mu = s * (1.0f / 512.0f);
  float q = 0.f;
#pragma unroll
  for (int i = 0; i < 8; ++i) { float d = v[i] - mu; q += d * d; }
#pragma unroll
  for (int off = 32; off; off >>= 1) q += __shfl_xor(q, off);
  float rstd = rsqrtf(q * (1.0f / 512.0f) + 1e-5f);
  us8 o;
#pragma unroll
  for (int i = 0; i < 8; ++i) {
    int col = lane * 8 + i;
    o[i] = bf16u((v[i] - mu) * rstd * g[col] + b[col]);
  }
  *(us8*)(outb + (size_t)row * kD + lane * 8) = o;
}

// ============ MFMA GEMM, B^T input: C[M][N] = A[M][K] @ Bt[N][K]^T ==========
// 128 x TN tile, 256 threads (4 waves), BK=32, global_load_lds width 16.
// EPI: 0 = fp32 out, 1 = bf16 out, 2 = bias+relu+bf16, 3 = bias+bf16.
template <int TN, int EPI>
__global__ __launch_bounds__(256) void mfma_gemm_bt(
    const unsigned short* __restrict__ A, const unsigned short* __restrict__ Bt,
    int K, const float* __restrict__ bias, void* __restrict__ Cv, int N) {
  constexpr int MI = (TN == 128) ? 4 : 2;
  constexpr int NJ = 4;
  constexpr int BCH = TN * 64 / 1024;
  __shared__ __align__(16) unsigned short As[128 * kBK];
  __shared__ __align__(16) unsigned short Bs[TN * kBK];
  const int tid = threadIdx.x;
  const int lane = tid & 63, wv = tid >> 6;
  const int ml = lane & 15, qd = lane >> 4;
  const int m0 = blockIdx.y * 128, n0 = blockIdx.x * TN;
  const int mw0 = (TN == 128) ? (wv >> 1) * 64 : wv * 32;
  const int nw0 = (TN == 128) ? (wv & 1) * 64 : 0;
  const size_t ldA = (size_t)K * 2, ldB = (size_t)K * 2;
  const char* Ab = (const char*)A + (size_t)m0 * ldA;
  const char* Bb = (const char*)Bt + (size_t)n0 * ldB;
  f32x4 acc[MI][NJ];
#pragma unroll
  for (int i = 0; i < MI; ++i)
#pragma unroll
    for (int j = 0; j < NJ; ++j) acc[i][j] = (f32x4)0.f;
  for (int k0 = 0; k0 < K; k0 += kBK) {
#pragma unroll
    for (int c = wv; c < 8; c += 4) {
      int fb = c * 1024 + lane * 16;
      gl_lds16(Ab + (size_t)(fb >> 6) * ldA + (fb & 63) + (size_t)k0 * 2,
               (char*)As + c * 1024);
    }
#pragma unroll
    for (int c = wv; c < BCH; c += 4) {
      int fb = c * 1024 + lane * 16;
      gl_lds16(Bb + (size_t)(fb >> 6) * ldB + (fb & 63) + (size_t)k0 * 2,
               (char*)Bs + c * 1024);
    }
    __syncthreads();
    bf16x8 af[MI], bfr[NJ];
#pragma unroll
    for (int i = 0; i < MI; ++i)
      af[i] = *(const bf16x8*)(As + (mw0 + i * 16 + ml) * kBK + qd * 8);
#pragma unroll
    for (int j = 0; j < NJ; ++j)
      bfr[j] = *(const bf16x8*)(Bs + (nw0 + j * 16 + ml) * kBK + qd * 8);
#pragma unroll
    for (int i = 0; i < MI; ++i)
#pragma unroll
      for (int j = 0; j < NJ; ++j)
        acc[i][j] = __builtin_amdgcn_mfma_f32_16x16x32_bf16(af[i], bfr[j], acc[i][j], 0, 0, 0);
    __syncthreads();
  }
#pragma unroll
  for (int i = 0; i < MI; ++i)
#pragma unroll
    for (int j = 0; j < NJ; ++j)
#pragma unroll
      for (int r = 0; r < 4; ++r) {
        int m = m0 + mw0 + i * 16 + qd * 4 + r;
        int n = n0 + nw0 + j * 16 + ml;
        float val = acc[i][j][r];
        if (EPI >= 2) val += bias[n];
        if (EPI == 2) val = fmaxf(val, 0.f);
        size_t idx = (size_t)m * N + n;
        if (EPI == 0) ((float*)Cv)[idx] = val;
        else ((unsigned short*)Cv)[idx] = bf16u(val);
      }
}

// ====== gate r: 128x64 tile, wave=64x32 (acc 8 f32x4 -> low reg pressure) ==
// acc = Y@W0t^T + X@W1t^T ; RX = bf16(sigmoid(acc+b0+b1)*x)
__global__ __launch_bounds__(256, 4) void mfma_gate_r(
    const unsigned short* __restrict__ Yb, const unsigned short* __restrict__ Xb,
    const unsigned short* __restrict__ Wt, const float* __restrict__ gb,
    unsigned short* __restrict__ RX) {
  __shared__ __align__(16) unsigned short As[128 * kBK];  // 8 KB
  __shared__ __align__(16) unsigned short Bs[64 * kBK];   // 4 KB
  const int tid = threadIdx.x;
  const int lane = tid & 63, wv = tid >> 6;
  const int ml = lane & 15, qd = lane >> 4;
  const int m0 = blockIdx.y * 128, n0 = blockIdx.x * 64;
  const int mw0 = (wv >> 1) * 64, nw0 = (wv & 1) * 32;
  const size_t ld = (size_t)kD * 2;
  f32x4 acc[4][2];
#pragma unroll
  for (int i = 0; i < 4; ++i)
#pragma unroll
    for (int j = 0; j < 2; ++j) acc[i][j] = (f32x4)0.f;
  for (int p = 0; p < 2; ++p) {
    const char* Ab = (const char*)(p ? Xb : Yb) + (size_t)m0 * ld;
    const char* Bb = (const char*)(Wt + (size_t)p * kD * kD) + (size_t)n0 * ld;
    for (int k0 = 0; k0 < kD; k0 += kBK) {
#pragma unroll
      for (int c = wv; c < 8; c += 4) {
        int fb = c * 1024 + lane * 16;
        gl_lds16(Ab + (size_t)(fb >> 6) * ld + (fb & 63) + (size_t)k0 * 2,
                 (char*)As + c * 1024);
      }
      {
        int fb = wv * 1024 + lane * 16;
        gl_lds16(Bb + (size_t)(fb >> 6) * ld + (fb & 63) + (size_t)k0 * 2,
                 (char*)Bs + wv * 1024);
      }
      __syncthreads();
      bf16x8 af[4], bfr[2];
#pragma unroll
      for (int i = 0; i < 4; ++i)
        af[i] = *(const bf16x8*)(As + (mw0 + i * 16 + ml) * kBK + qd * 8);
#pragma unroll
      for (int j = 0; j < 2; ++j)
        bfr[j] = *(const bf16x8*)(Bs + (nw0 + j * 16 + ml) * kBK + qd * 8);
#pragma unroll
      for (int i = 0; i < 4; ++i)
#pragma unroll
        for (int j = 0; j < 2; ++j)
          acc[i][j] = __builtin_amdgcn_mfma_f32_16x16x32_bf16(af[i], bfr[j], acc[i][j], 0, 0, 0);
      __syncthreads();
    }
  }
#pragma unroll
  for (int i = 0; i < 4; ++i)
#pragma unroll
    for (int j = 0; j < 2; ++j)
#pragma unroll
      for (int r = 0; r < 4; ++r) {
        int m = m0 + mw0 + i * 16 + qd * 4 + r;
        int n = n0 + nw0 + j * 16 + ml;
        float rg = sigmoidf_(acc[i][j][r] + gb[n] + gb[kD + n]);
        size_t idx = (size_t)m * kD + n;
        RX[idx] = bf16u(rg * b2f(Xb[idx]));
      }
}

// ====== gate h+z: 128x64 tile, wave=64x32, 4 sequential passes, 2 accs =====
// accH = Y@W4 + RX@W5 ; accZ = Y@W2 + X@W3
// out = (1-z)*x + z*tanh(accH+b4+b5), z = sigmoid(accZ+b2+b3-BG), x bf16.
// POOL=false: OUTb bf16. POOL=true: atomic mean-pool into TS.
template <bool POOL>
__global__ __launch_bounds__(256, 3) void mfma_gate_hz(
    const unsigned short* __restrict__ Yb, const unsigned short* __restrict__ RXb,
    const unsigned short* __restrict__ Xb, const unsigned short* __restrict__ Wt,
    const float* __restrict__ gb, unsigned short* __restrict__ OUTb,
    float* __restrict__ TS, int rowoff) {
  __shared__ __align__(16) unsigned short As[128 * kBK];  // 8 KB
  __shared__ __align__(16) unsigned short Bs[64 * kBK];   // 4 KB
  const int tid = threadIdx.x;
  const int lane = tid & 63, wv = tid >> 6;
  const int ml = lane & 15, qd = lane >> 4;
  const int m0 = blockIdx.y * 128, n0 = blockIdx.x * 64;
  const int mw0 = (wv >> 1) * 64, nw0 = (wv & 1) * 32;
  const size_t ld = (size_t)kD * 2;
  const size_t DD = (size_t)kD * kD;
  f32x4 accH[4][2], accZ[4][2];
#pragma unroll
  for (int i = 0; i < 4; ++i)
#pragma unroll
    for (int j = 0; j < 2; ++j) { accH[i][j] = (f32x4)0.f; accZ[i][j] = (f32x4)0.f; }
  const unsigned short* Ap[4] = {Yb, RXb, Yb, Xb};
  const int wsel[4] = {4, 5, 2, 3};
  for (int p = 0; p < 4; ++p) {
    const char* Ab = (const char*)Ap[p] + (size_t)m0 * ld;
    const char* Bb = (const char*)(Wt + (size_t)wsel[p] * DD) + (size_t)n0 * ld;
    f32x4 (*acc)[2] = (p < 2) ? accH : accZ;
    for (int k0 = 0; k0 < kD; k0 += kBK) {
#pragma unroll
      for (int c = wv; c < 8; c += 4) {
        int fb = c * 1024 + lane * 16;
        gl_lds16(Ab + (size_t)(fb >> 6) * ld + (fb & 63) + (size_t)k0 * 2,
                 (char*)As + c * 1024);
      }
      {
        int fb = wv * 1024 + lane * 16;
        gl_lds16(Bb + (size_t)(fb >> 6) * ld + (fb & 63) + (size_t)k0 * 2,
                 (char*)Bs + wv * 1024);
      }
      __syncthreads();
      bf16x8 af[4], bfr[2];
#pragma unroll
      for (int i = 0; i < 4; ++i)
        af[i] = *(const bf16x8*)(As + (mw0 + i * 16 + ml) * kBK + qd * 8);
#pragma unroll
      for (int j = 0; j < 2; ++j)
        bfr[j] = *(const bf16x8*)(Bs + (nw0 + j * 16 + ml) * kBK + qd * 8);
#pragma unroll
      for (int i = 0; i < 4; ++i)
#pragma unroll
        for (int j = 0; j < 2; ++j)
          acc[i][j] = __builtin_amdgcn_mfma_f32_16x16x32_bf16(af[i], bfr[j], acc[i][j], 0, 0, 0);
      __syncthreads();
    }
  }
#pragma unroll
  for (int i = 0; i < 4; ++i)
#pragma unroll
    for (int j = 0; j < 2; ++j)
#pragma unroll
      for (int r = 0; r < 4; ++r) {
        int m = m0 + mw0 + i * 16 + qd * 4 + r;
        int n = n0 + nw0 + j * 16 + ml;
        float z = sigmoidf_(accZ[i][j][r] + gb[2 * kD + n] + gb[3 * kD + n] - kBG);
        float hc = tanhf(accH[i][j][r] + gb[4 * kD + n] + gb[5 * kD + n]);
        size_t idx = (size_t)m * kD + n;
        float val = (1.0f - z) * b2f(Xb[idx]) + z * hc;
        if (POOL) {
          int b = (rowoff + m) & (kB - 1);
          atomicAdd(TS + (size_t)b * kD + n, val * (1.0f / kT));
        } else {
          OUTb[idx] = bf16u(val);
        }
      }
}

// -------- Positional embedding projection ----------
__global__ __launch_bounds__(64) void posp_kernel(const float* __restrict__ Wp,
                                                  float* __restrict__ P) {
  __shared__ float emb[512];
  int jj = blockIdx.x;
  int t = threadIdx.x;
  float pos = (float)(kJ - 1 - jj);
#pragma unroll
  for (int r = 0; r < 8; ++r) {
    int d = t + r * 64;
    int i = (d < 256) ? d : d - 256;
    float invf = expf(-((float)(2 * i) * (1.0f / 512.0f)) * 9.210340371976184f);
    float si = pos * invf;
    emb[d] = (d < 256) ? sinf(si) : cosf(si);
  }
  __syncthreads();
  float acc = 0.f;
  for (int d = 0; d < 512; ++d) acc = fmaf(emb[d], Wp[d * 64 + t], acc);
  P[jj * 64 + t] = acc;
}

// -------- Attention (fp32 math), KV bf16 in, AV out as bf16 ----------
__global__ __launch_bounds__(128) void attn_kernel(
    const float* __restrict__ Q, const unsigned short* __restrict__ KV,
    const float* __restrict__ P, const float* __restrict__ U,
    const float* __restrict__ V, unsigned short* __restrict__ AV) {
  __shared__ float ks[kJ][32];
  __shared__ float vs[kJ][32];
  __shared__ float ps[32][kJ + 2];
  const int b = blockIdx.x, h = blockIdx.y;
  const int tid = threadIdx.x;
  for (int idx = tid; idx < kJ * 8; idx += 128) {
    int j = idx >> 3, seg = idx & 7;
    const unsigned short* src = KV + ((size_t)(j * kB + b)) * 128 + h * 32 + seg * 4;
    us4 kq = *(const us4*)src;
    us4 vq = *(const us4*)(src + 64);
#pragma unroll
    for (int e = 0; e < 4; ++e) {
      ks[j][seg * 4 + e] = b2f(kq[e]);
      vs[j][seg * 4 + e] = b2f(vq[e]);
    }
  }
  for (int idx = tid; idx < kJ * 8; idx += 128) {
    int j = idx >> 3, seg = idx & 7;
    float4 pq = *(const float4*)(P + j * 64 + h * 32 + seg * 4);
    ps[seg * 4 + 0][j] = pq.x;
    ps[seg * 4 + 1][j] = pq.y;
    ps[seg * 4 + 2][j] = pq.z;
    ps[seg * 4 + 3][j] = pq.w;
  }
  __syncthreads();
  const int i = tid;
  float qu[32], qv[32];
  const float* qp = Q + ((size_t)(i * kB + b)) * 64 + h * 32;
#pragma unroll
  for (int d = 0; d < 32; ++d) {
    float qd = qp[d];
    qu[d] = qd + U[h * 32 + d];
    qv[d] = qd + V[h * 32 + d];
  }
  float m = -INFINITY, l = 0.f, acc[32] = {};
  const float scale = 0.17677669529663687f;
  for (int j = 0; j <= i + kM; ++j) {
    float s = 0.f;
#pragma unroll
    for (int d = 0; d < 32; d += 4) {
      float4 k4 = *(const float4*)&ks[j][d];
      s = fmaf(qu[d + 0], k4.x, s);
      s = fmaf(qu[d + 1], k4.y, s);
      s = fmaf(qu[d + 2], k4.z, s);
      s = fmaf(qu[d + 3], k4.w, s);
    }
    int jj = j + (kT - 1) - i;
#pragma unroll
    for (int d = 0; d < 32; ++d) s = fmaf(qv[d], ps[d][jj], s);
    float ls = s * scale;
    float nm = fmaxf(m, ls);
    float w = __expf(ls - nm);
    float f = __expf(m - nm);
    l = l * f + w;
#pragma unroll
    for (int d = 0; d < 32; d += 4) {
      float4 v4 = *(const float4*)&vs[j][d];
      acc[d + 0] = fmaf(acc[d + 0], f, w * v4.x);
      acc[d + 1] = fmaf(acc[d + 1], f, w * v4.y);
      acc[d + 2] = fmaf(acc[d + 2], f, w * v4.z);
      acc[d + 3] = fmaf(acc[d + 3], f, w * v4.w);
    }
    m = nm;
  }
  float inv = 1.0f / l;
  unsigned short* o = AV + ((size_t)(i * kB + b)) * 64 + h * 32;
#pragma unroll
  for (int d = 0; d < 32; ++d) o[d] = bf16u(acc[d] * inv);
}

// -------- fp32 fallback GEMM for the small critic head --------
template <int ACTF, bool DUAL>
__global__ __launch_bounds__(256) void gemm_kernel(
    const float* __restrict__ A1, const float* __restrict__ Bm1, int K1,
    const float* __restrict__ A2, const float* __restrict__ Bm2, int K2,
    const float* __restrict__ bias, float* __restrict__ C, int Mrows, int N) {
  __shared__ float As[16][68];
  __shared__ float Bs[16][68];
  const int tid = threadIdx.x;
  const int tx = tid & 15, ty = tid >> 4;
  const int m0 = blockIdx.y * 64, n0 = blockIdx.x * 64;
  const int ar = tid >> 2, aseg = tid & 3;
  float acc[4][4] = {};
#pragma unroll
  for (int pass = 0; pass < (DUAL ? 2 : 1); ++pass) {
    const float* A = (DUAL && pass) ? A2 : A1;
    const float* Bm = (DUAL && pass) ? Bm2 : Bm1;
    const int K = (DUAL && pass) ? K2 : K1;
    for (int k0 = 0; k0 < K; k0 += 16) {
      {
        int row = m0 + ar;
        int kb = k0 + aseg * 4;
        float x0 = 0.f, x1 = 0.f, x2 = 0.f, x3 = 0.f;
        if (row < Mrows) {
          const float* ap = A + (size_t)row * K + kb;
          if (kb + 3 < K) {
            float4 t = *(const float4*)ap;
            x0 = t.x; x1 = t.y; x2 = t.z; x3 = t.w;
          } else {
            if (kb + 0 < K) x0 = ap[0];
            if (kb + 1 < K) x1 = ap[1];
            if (kb + 2 < K) x2 = ap[2];
          }
        }
        As[aseg * 4 + 0][ar] = x0;
        As[aseg * 4 + 1][ar] = x1;
        As[aseg * 4 + 2][ar] = x2;
        As[aseg * 4 + 3][ar] = x3;
      }
      {
        int krow = k0 + ty;
        int nb = n0 + tx * 4;
        float y0 = 0.f, y1 = 0.f, y2 = 0.f, y3 = 0.f;
        if (krow < K) {
          const float* bp = Bm + (size_t)krow * N + nb;
          if (nb + 3 < N) {
            float4 t = *(const float4*)bp;
            y0 = t.x; y1 = t.y; y2 = t.z; y3 = t.w;
          } else {
            if (nb + 0 < N) y0 = bp[0];
            if (nb + 1 < N) y1 = bp[1];
            if (nb + 2 < N) y2 = bp[2];
          }
        }
        *(float4*)&Bs[ty][tx * 4] = make_float4(y0, y1, y2, y3);
      }
      __syncthreads();
#pragma unroll
      for (int kk = 0; kk < 16; ++kk) {
        float a[4], bb[4];
        *(float4*)a = *(const float4*)&As[kk][ty * 4];
        *(float4*)bb = *(const float4*)&Bs[kk][tx * 4];
#pragma unroll
        for (int i = 0; i < 4; ++i)
#pragma unroll
          for (int j = 0; j < 4; ++j) acc[i][j] = fmaf(a[i], bb[j], acc[i][j]);
      }
      __syncthreads();
    }
  }
#pragma unroll
  for (int i = 0; i < 4; ++i) {
    int m = m0 + ty * 4 + i;
    if (m >= Mrows) continue;
#pragma unroll
    for (int j = 0; j < 4; ++j) {
      int n = n0 + tx * 4 + j;
      if (n >= N) continue;
      float val = acc[i][j];
      if (bias) val += bias[n];
      if (ACTF == 1) val = fmaxf(val, 0.f);
      C[(size_t)m * N + n] = val;
    }
  }
}

}  // namespace

extern "C" void kernel_launch(void* const* d_in, const int* in_sizes, int n_in,
                              void* d_out, int out_size, void* d_ws, size_t ws_size,
                              hipStream_t stream) {
  (void)in_sizes; (void)n_in; (void)out_size;
  const float* aug    = (const float*)d_in[0];
  const float* action = (const float*)d_in[1];
  const float* memory = (const float*)d_in[2];
  const float* W_q    = (const float*)d_in[3];
  const float* W_kv   = (const float*)d_in[4];
  const float* W_p    = (const float*)d_in[5];
  const float* W_out  = (const float*)d_in[6];
  const float* u      = (const float*)d_in[7];
  const float* v      = (const float*)d_in[8];
  const float* ln1_g  = (const float*)d_in[9];
  const float* ln1_b  = (const float*)d_in[10];
  const float* ln2_g  = (const float*)d_in[11];
  const float* ln2_b  = (const float*)d_in[12];
  const float* ff_W1  = (const float*)d_in[13];
  const float* ff_b1  = (const float*)d_in[14];
  const float* ff_W2  = (const float*)d_in[15];
  const float* ff_b2  = (const float*)d_in[16];
  const float* g1_W   = (const float*)d_in[17];
  const float* g1_b   = (const float*)d_in[18];
  const float* g2_W   = (const float*)d_in[19];
  const float* g2_b   = (const float*)d_in[20];
  const float* d1_W   = (const float*)d_in[21];
  const float* d1_b   = (const float*)d_in[22];
  const float* d2_W   = (const float*)d_in[23];
  const float* d2_b   = (const float*)d_in[24];
  const float* d3_W   = (const float*)d_in[25];
  const float* d3_b   = (const float*)d_in[26];
  const float* d4_W   = (const float*)d_in[27];
  const float* d4_b   = (const float*)d_in[28];
  float* out = (float*)d_out;

  // ---------------- workspace carve ----------------
  char* base = (char*)d_ws;
  auto alloc = [&](size_t bytes) -> char* {
    char* p = base;
    base += (bytes + 255) & ~(size_t)255;
    return p;
  };
  unsigned short* Wqt  = (unsigned short*)alloc((size_t)64 * 512 * 2);
  unsigned short* Wkvt = (unsigned short*)alloc((size_t)128 * 512 * 2);
  unsigned short* Wot  = (unsigned short*)alloc((size_t)512 * 64 * 2);
  unsigned short* Wf1t = (unsigned short*)alloc((size_t)64 * 512 * 2);
  unsigned short* Wf2t = (unsigned short*)alloc((size_t)512 * 64 * 2);
  unsigned short* G1t  = (unsigned short*)alloc((size_t)6 * 512 * 512 * 2);
  unsigned short* G2t  = (unsigned short*)alloc((size_t)6 * 512 * 512 * 2);
  unsigned short* Memb = (unsigned short*)alloc((size_t)3072 * 512 * 2);
  unsigned short* KVb  = (unsigned short*)alloc((size_t)kJ * kB * 128 * 2);
  float* Qb  = (float*)alloc((size_t)kTB * 64 * 4);
  unsigned short* AVb = (unsigned short*)alloc((size_t)kTB * 64 * 2);
  unsigned short* Xb  = (unsigned short*)alloc((size_t)kTB * kD * 2);  // raw aug bf16
  float* Pb  = (float*)alloc((size_t)kJ * 64 * 4);
  float* TSb = (float*)alloc((size_t)kB * kD * 4);
  float* H1b = (float*)alloc((size_t)kB * 1024 * 4);
  float* H2b = (float*)alloc((size_t)kB * 512 * 4);
  float* H3b = (float*)alloc((size_t)kB * 320 * 4);
  size_t fixedBytes = (size_t)(base - (char*)d_ws);
  const size_t ln1Bytes = (size_t)kTB * kD * 2;  // L1b overlaps chunk region
  int nch = 1;
  while (nch < 32) {
    size_t chunkBytes = (size_t)(kTB / nch) * 4224 + 4096;
    size_t reuse = chunkBytes > ln1Bytes ? chunkBytes : ln1Bytes;
    if (fixedBytes + reuse <= ws_size) break;
    nch <<= 1;
  }
  const int CR = kTB / nch;
  char* R = base;
  unsigned short* L1b = (unsigned short*)R;  // ln1(aug) bf16 (dead before chunks)
  char* rp = R;
  auto ralloc = [&](size_t bytes) -> char* {
    char* p = rp;
    rp += (bytes + 255) & ~(size_t)255;
    return p;
  };
  unsigned short* Ycb   = (unsigned short*)ralloc((size_t)CR * 512 * 2);
  unsigned short* RXcb  = (unsigned short*)ralloc((size_t)CR * 512 * 2);
  unsigned short* SRCcb = (unsigned short*)ralloc((size_t)CR * 512 * 2);
  unsigned short* LN2cb = (unsigned short*)ralloc((size_t)CR * 512 * 2);
  unsigned short* F1cb  = (unsigned short*)ralloc((size_t)CR * 64 * 2);

  const float* np = nullptr;

  // -------- prep --------
  hipMemsetAsync(TSb, 0, (size_t)kB * kD * sizeof(float), stream);
  transp_kernel<<<dim3(2, 16, 1), 256, 0, stream>>>(W_q, Wqt, 512, 64);
  transp_kernel<<<dim3(4, 16, 1), 256, 0, stream>>>(W_kv, Wkvt, 512, 128);
  transp_kernel<<<dim3(16, 2, 1), 256, 0, stream>>>(W_out, Wot, 64, 512);
  transp_kernel<<<dim3(2, 16, 1), 256, 0, stream>>>(ff_W1, Wf1t, 512, 64);
  transp_kernel<<<dim3(16, 2, 1), 256, 0, stream>>>(ff_W2, Wf2t, 64, 512);
  transp_kernel<<<dim3(16, 16, 6), 256, 0, stream>>>(g1_W, G1t, 512, 512);
  transp_kernel<<<dim3(16, 16, 6), 256, 0, stream>>>(g2_W, G2t, 512, 512);
  conv_bf16_kernel<<<(3072 * 512 / 8 + 255) / 256, 256, 0, stream>>>(
      memory, Memb, (size_t)3072 * 512);
  // ln1(aug) -> L1b bf16 and raw aug -> Xb bf16 (one fp32 read)
  ln1_dual_kernel<<<kTB / 4, 256, 0, stream>>>(aug, ln1_g, ln1_b, L1b, Xb, kTB);
  // kv = [memory; ln1] @ W_kv  (bf16 out)
  mfma_gemm_bt<128, 1><<<dim3(1, 3072 / 128), 256, 0, stream>>>(
      Memb, Wkvt, 512, np, KVb, 128);
  mfma_gemm_bt<128, 1><<<dim3(1, kTB / 128), 256, 0, stream>>>(
      L1b, Wkvt, 512, np, KVb + (size_t)3072 * 128, 128);
  // q = ln1 @ W_q (fp32 out)
  mfma_gemm_bt<64, 0><<<dim3(1, kTB / 128), 256, 0, stream>>>(
      L1b, Wqt, 512, np, Qb, 64);
  posp_kernel<<<kJ, 64, 0, stream>>>(W_p, Pb);
  attn_kernel<<<dim3(kB, kH), 128, 0, stream>>>(Qb, KVb, Pb, u, v, AVb);

  for (int c = 0; c < nch; ++c) {
    const int R0 = c * CR;
    const unsigned short* Xc = Xb + (size_t)R0 * kD;
    // y1 = av @ W_out (bf16 out)
    mfma_gemm_bt<128, 1><<<dim3(4, CR / 128), 256, 0, stream>>>(
        AVb + (size_t)R0 * 64, Wot, 64, np, Ycb, 512);
    // gate1
    mfma_gate_r<<<dim3(8, CR / 128), 256, 0, stream>>>(Ycb, Xc, G1t, g1_b, RXcb);
    mfma_gate_hz<false><<<dim3(8, CR / 128), 256, 0, stream>>>(
        Ycb, RXcb, Xc, G1t, g1_b, SRCcb, nullptr, R0);
    // ln2 (bf16 in/out)
    ln_b16_kernel<<<CR / 4, 256, 0, stream>>>(SRCcb, ln2_g, ln2_b, LN2cb, CR);
    // ff1 = relu(ln2 @ ff_W1 + b1) (bf16 out)
    mfma_gemm_bt<64, 2><<<dim3(1, CR / 128), 256, 0, stream>>>(
        LN2cb, Wf1t, 512, ff_b1, F1cb, 64);
    // y2 = ff1 @ ff_W2 + b2 (bf16 out)
    mfma_gemm_bt<128, 3><<<dim3(4, CR / 128), 256, 0, stream>>>(
        F1cb, Wf2t, 64, ff_b2, Ycb, 512);
    // gate2 + fused mean-pool
    mfma_gate_r<<<dim3(8, CR / 128), 256, 0, stream>>>(Ycb, SRCcb, G2t, g2_b, RXcb);
    mfma_gate_hz<true><<<dim3(8, CR / 128), 256, 0, stream>>>(
        Ycb, RXcb, SRCcb, G2t, g2_b, nullptr, TSb, R0);
  }

  // critic head (fp32)
  gemm_kernel<1, false><<<dim3(16, kB / 64), 256, 0, stream>>>(
      TSb, d1_W, 512, np, np, 0, d1_b, H1b, kB, 1024);
  gemm_kernel<1, true><<<dim3(8, kB / 64), 256, 0, stream>>>(
      H1b, d2_W, 1024, action, d2_W + (size_t)1024 * 512, 64, d2_b, H2b, kB, 512);
  gemm_kernel<1, false><<<dim3(5, kB / 64), 256, 0, stream>>>(
      H2b, d3_W, 512, np, np, 0, d3_b, H3b, kB, 300);
  gemm_kernel<1, false><<<dim3(1, kB / 64), 256, 0, stream>>>(
      H3b, d4_W, 300, np, np, 0, d4_b, out, kB, 1);
}

// Round 6
// 1539.649 us; speedup vs baseline: 1.3845x; 1.1911x over previous
//
#include <hip/hip_runtime.h>
#include <math.h>

namespace {

constexpr int kT = 128, kB = 512, kD = 512, kM = 6, kH = 2;
constexpr int kJ = kT + kM;          // 134
constexpr float kBG = 0.1f;
constexpr int kTB = kT * kB;         // 65536 rows
constexpr int kBK = 32;              // K-tile for MFMA kernels

typedef __attribute__((ext_vector_type(8))) short bf16x8;
typedef __attribute__((ext_vector_type(4))) float f32x4;
typedef __attribute__((ext_vector_type(8))) unsigned short us8;
typedef __attribute__((ext_vector_type(4))) unsigned short us4;

__device__ __forceinline__ float sigmoidf_(float x) {
  return 1.0f / (1.0f + __expf(-x));
}

__device__ __forceinline__ unsigned short bf16u(float f) {
  union { float f; unsigned u; } c; c.f = f;
  unsigned r = c.u + 0x7fffu + ((c.u >> 16) & 1u);
  return (unsigned short)(r >> 16);
}

__device__ __forceinline__ float b2f(unsigned short u) {
  union { unsigned u; float f; } c; c.u = (unsigned)u << 16;
  return c.f;
}

__device__ __forceinline__ void gl_lds16(const void* g, void* l) {
  __builtin_amdgcn_global_load_lds(
      (const __attribute__((address_space(1))) unsigned int*)g,
      (__attribute__((address_space(3))) unsigned int*)l, 16, 0, 0);
}

// ---- transpose + cast: W fp32 [K][N] -> Wt bf16 [N][K]; dims mult of 32 ----
__global__ __launch_bounds__(256) void transp_kernel(const float* __restrict__ W,
                                                     unsigned short* __restrict__ Wt,
                                                     int K, int N) {
  __shared__ float t[32][33];
  const int n0 = blockIdx.x * 32, k0 = blockIdx.y * 32;
  const float* Wb = W + (size_t)blockIdx.z * K * N;
  unsigned short* Wtb = Wt + (size_t)blockIdx.z * K * N;
  int tx = threadIdx.x & 31, ty = threadIdx.x >> 5;  // 32 x 8
#pragma unroll
  for (int r = 0; r < 32; r += 8)
    t[ty + r][tx] = Wb[(size_t)(k0 + ty + r) * N + n0 + tx];
  __syncthreads();
#pragma unroll
  for (int r = 0; r < 32; r += 8)
    Wtb[(size_t)(n0 + ty + r) * K + k0 + tx] = bf16u(t[tx][ty + r]);
}

// ---- fp32 -> bf16 elementwise (n multiple of 8) ----
__global__ __launch_bounds__(256) void conv_bf16_kernel(const float* __restrict__ in,
                                                        unsigned short* __restrict__ outb,
                                                        size_t n) {
  size_t idx = ((size_t)blockIdx.x * 256 + threadIdx.x) * 8;
  if (idx >= n) return;
  float4 a = *(const float4*)(in + idx);
  float4 c = *(const float4*)(in + idx + 4);
  us8 o;
  o[0] = bf16u(a.x); o[1] = bf16u(a.y); o[2] = bf16u(a.z); o[3] = bf16u(a.w);
  o[4] = bf16u(c.x); o[5] = bf16u(c.y); o[6] = bf16u(c.z); o[7] = bf16u(c.w);
  *(us8*)(outb + idx) = o;
}

// ---- LN1 dual-output: LN(x) -> bf16 AND raw x -> bf16, one fp32 read ----
__global__ __launch_bounds__(256) void ln1_dual_kernel(const float* __restrict__ in,
                                                       const float* __restrict__ g,
                                                       const float* __restrict__ b,
                                                       unsigned short* __restrict__ outLN,
                                                       unsigned short* __restrict__ outRaw,
                                                       int nrows) {
  int wave = threadIdx.x >> 6, lane = threadIdx.x & 63;
  int row = blockIdx.x * 4 + wave;
  if (row >= nrows) return;
  const float* p = in + (size_t)row * kD + lane * 8;
  float4 a = *(const float4*)p;
  float4 c = *(const float4*)(p + 4);
  float v[8] = {a.x, a.y, a.z, a.w, c.x, c.y, c.z, c.w};
  float s = 0.f;
#pragma unroll
  for (int i = 0; i < 8; ++i) s += v[i];
#pragma unroll
  for (int off = 32; off; off >>= 1) s += __shfl_xor(s, off);
  float mu = s * (1.0f / 512.0f);
  float q = 0.f;
#pragma unroll
  for (int i = 0; i < 8; ++i) { float d = v[i] - mu; q += d * d; }
#pragma unroll
  for (int off = 32; off; off >>= 1) q += __shfl_xor(q, off);
  float rstd = rsqrtf(q * (1.0f / 512.0f) + 1e-5f);
  us8 oln, oraw;
#pragma unroll
  for (int i = 0; i < 8; ++i) {
    int col = lane * 8 + i;
    oln[i] = bf16u((v[i] - mu) * rstd * g[col] + b[col]);
    oraw[i] = bf16u(v[i]);
  }
  size_t off8 = (size_t)row * kD + lane * 8;
  *(us8*)(outLN + off8) = oln;
  *(us8*)(outRaw + off8) = oraw;
}

// ---- LN with bf16 input -> bf16 out ----
__global__ __launch_bounds__(256) void ln_b16_kernel(const unsigned short* __restrict__ in,
                                                     const float* __restrict__ g,
                                                     const float* __restrict__ b,
                                                     unsigned short* __restrict__ outb,
                                                     int nrows) {
  int wave = threadIdx.x >> 6, lane = threadIdx.x & 63;
  int row = blockIdx.x * 4 + wave;
  if (row >= nrows) return;
  us8 iv = *(const us8*)(in + (size_t)row * kD + lane * 8);
  float v[8];
#pragma unroll
  for (int i = 0; i < 8; ++i) v[i] = b2f(iv[i]);
  float s = 0.f;
#pragma unroll
  for (int i = 0; i < 8; ++i) s += v[i];
#pragma unroll
  for (int off = 32; off; off >>= 1) s += __shfl_xor(s, off);
  float mu = s * (1.0f / 512.0f);
  float q = 0.f;
#pragma unroll
  for (int i = 0; i < 8; ++i) { float d = v[i] - mu; q += d * d; }
#pragma unroll
  for (int off = 32; off; off >>= 1) q += __shfl_xor(q, off);
  float rstd = rsqrtf(q * (1.0f / 512.0f) + 1e-5f);
  us8 o;
#pragma unroll
  for (int i = 0; i < 8; ++i) {
    int col = lane * 8 + i;
    o[i] = bf16u((v[i] - mu) * rstd * g[col] + b[col]);
  }
  *(us8*)(outb + (size_t)row * kD + lane * 8) = o;
}

// ============ MFMA GEMM, B^T input: C[M][N] = A[M][K] @ Bt[N][K]^T ==========
// 128 x TN tile, 256 threads (4 waves), BK=32, global_load_lds width 16.
// EPI: 0 = fp32 out, 1 = bf16 out, 2 = bias+relu+bf16, 3 = bias+bf16.
template <int TN, int EPI>
__global__ __launch_bounds__(256) void mfma_gemm_bt(
    const unsigned short* __restrict__ A, const unsigned short* __restrict__ Bt,
    int K, const float* __restrict__ bias, void* __restrict__ Cv, int N) {
  constexpr int MI = (TN == 128) ? 4 : 2;
  constexpr int NJ = 4;
  constexpr int BCH = TN * 64 / 1024;
  __shared__ __align__(16) unsigned short As[128 * kBK];
  __shared__ __align__(16) unsigned short Bs[TN * kBK];
  const int tid = threadIdx.x;
  const int lane = tid & 63, wv = tid >> 6;
  const int ml = lane & 15, qd = lane >> 4;
  const int m0 = blockIdx.y * 128, n0 = blockIdx.x * TN;
  const int mw0 = (TN == 128) ? (wv >> 1) * 64 : wv * 32;
  const int nw0 = (TN == 128) ? (wv & 1) * 64 : 0;
  const size_t ldA = (size_t)K * 2, ldB = (size_t)K * 2;
  const char* Ab = (const char*)A + (size_t)m0 * ldA;
  const char* Bb = (const char*)Bt + (size_t)n0 * ldB;
  f32x4 acc[MI][NJ];
#pragma unroll
  for (int i = 0; i < MI; ++i)
#pragma unroll
    for (int j = 0; j < NJ; ++j) acc[i][j] = (f32x4)0.f;
  for (int k0 = 0; k0 < K; k0 += kBK) {
#pragma unroll
    for (int c = wv; c < 8; c += 4) {
      int fb = c * 1024 + lane * 16;
      gl_lds16(Ab + (size_t)(fb >> 6) * ldA + (fb & 63) + (size_t)k0 * 2,
               (char*)As + c * 1024);
    }
#pragma unroll
    for (int c = wv; c < BCH; c += 4) {
      int fb = c * 1024 + lane * 16;
      gl_lds16(Bb + (size_t)(fb >> 6) * ldB + (fb & 63) + (size_t)k0 * 2,
               (char*)Bs + c * 1024);
    }
    __syncthreads();
    bf16x8 af[MI], bfr[NJ];
#pragma unroll
    for (int i = 0; i < MI; ++i)
      af[i] = *(const bf16x8*)(As + (mw0 + i * 16 + ml) * kBK + qd * 8);
#pragma unroll
    for (int j = 0; j < NJ; ++j)
      bfr[j] = *(const bf16x8*)(Bs + (nw0 + j * 16 + ml) * kBK + qd * 8);
#pragma unroll
    for (int i = 0; i < MI; ++i)
#pragma unroll
      for (int j = 0; j < NJ; ++j)
        acc[i][j] = __builtin_amdgcn_mfma_f32_16x16x32_bf16(af[i], bfr[j], acc[i][j], 0, 0, 0);
    __syncthreads();
  }
#pragma unroll
  for (int i = 0; i < MI; ++i)
#pragma unroll
    for (int j = 0; j < NJ; ++j)
#pragma unroll
      for (int r = 0; r < 4; ++r) {
        int m = m0 + mw0 + i * 16 + qd * 4 + r;
        int n = n0 + nw0 + j * 16 + ml;
        float val = acc[i][j][r];
        if (EPI >= 2) val += bias[n];
        if (EPI == 2) val = fmaxf(val, 0.f);
        size_t idx = (size_t)m * N + n;
        if (EPI == 0) ((float*)Cv)[idx] = val;
        else ((unsigned short*)Cv)[idx] = bf16u(val);
      }
}

// ====== gate r: 128x256 tile, 512 threads (8 waves, 2M x 4N), per-wave 64x64.
// acc = 16 f32x4 = 64 AGPR; ~120 total regs -> 4 waves/SIMD (50% occ).
// acc = Y@W0t^T + X@W1t^T ; RX = bf16(sigmoid(acc+b0+b1)*x)
__global__ __launch_bounds__(512, 4) void mfma_gate_r(
    const unsigned short* __restrict__ Yb, const unsigned short* __restrict__ Xb,
    const unsigned short* __restrict__ Wt, const float* __restrict__ gb,
    unsigned short* __restrict__ RX) {
  __shared__ __align__(16) unsigned short As[128 * kBK];   // 8 KB
  __shared__ __align__(16) unsigned short Bs[256 * kBK];   // 16 KB
  const int tid = threadIdx.x;
  const int lane = tid & 63, wv = tid >> 6;  // 8 waves
  const int ml = lane & 15, qd = lane >> 4;
  const int m0 = blockIdx.y * 128, n0 = blockIdx.x * 256;
  const int mw0 = (wv & 1) * 64, nw0 = (wv >> 1) * 64;
  const size_t ld = (size_t)kD * 2;
  f32x4 acc[4][4];
#pragma unroll
  for (int i = 0; i < 4; ++i)
#pragma unroll
    for (int j = 0; j < 4; ++j) acc[i][j] = (f32x4)0.f;
  for (int p = 0; p < 2; ++p) {
    const char* Ab = (const char*)(p ? Xb : Yb) + (size_t)m0 * ld;
    const char* Bb = (const char*)(Wt + (size_t)p * kD * kD) + (size_t)n0 * ld;
    for (int k0 = 0; k0 < kD; k0 += kBK) {
      {  // A: 8 chunks / 8 waves
        int fb = wv * 1024 + lane * 16;
        gl_lds16(Ab + (size_t)(fb >> 6) * ld + (fb & 63) + (size_t)k0 * 2,
                 (char*)As + wv * 1024);
      }
#pragma unroll
      for (int c = wv; c < 16; c += 8) {  // B: 16 chunks / 8 waves
        int fb = c * 1024 + lane * 16;
        gl_lds16(Bb + (size_t)(fb >> 6) * ld + (fb & 63) + (size_t)k0 * 2,
                 (char*)Bs + c * 1024);
      }
      __syncthreads();
      bf16x8 af[4], bfr[4];
#pragma unroll
      for (int i = 0; i < 4; ++i)
        af[i] = *(const bf16x8*)(As + (mw0 + i * 16 + ml) * kBK + qd * 8);
#pragma unroll
      for (int j = 0; j < 4; ++j)
        bfr[j] = *(const bf16x8*)(Bs + (nw0 + j * 16 + ml) * kBK + qd * 8);
#pragma unroll
      for (int i = 0; i < 4; ++i)
#pragma unroll
        for (int j = 0; j < 4; ++j)
          acc[i][j] = __builtin_amdgcn_mfma_f32_16x16x32_bf16(af[i], bfr[j], acc[i][j], 0, 0, 0);
      __syncthreads();
    }
  }
#pragma unroll
  for (int i = 0; i < 4; ++i)
#pragma unroll
    for (int j = 0; j < 4; ++j)
#pragma unroll
      for (int r = 0; r < 4; ++r) {
        int m = m0 + mw0 + i * 16 + qd * 4 + r;
        int n = n0 + nw0 + j * 16 + ml;
        float rg = sigmoidf_(acc[i][j][r] + gb[n] + gb[kD + n]);
        size_t idx = (size_t)m * kD + n;
        RX[idx] = bf16u(rg * b2f(Xb[idx]));
      }
}

// ====== gate h+z: 128x128 tile, 512 threads (8 waves, 4M x 2N), per-wave
// 32x64; accH+accZ = 2 x 8 f32x4 = 64 AGPR -> 4 waves/SIMD (50% occ).
// accH = Y@W4 + RX@W5 ; accZ = Y@W2 + X@W3 (4 sequential passes).
// out = (1-z)*x + z*tanh(accH+b4+b5), z = sigmoid(accZ+b2+b3-BG), x bf16.
// POOL=false: OUTb bf16. POOL=true: atomic mean-pool into TS.
template <bool POOL>
__global__ __launch_bounds__(512, 4) void mfma_gate_hz(
    const unsigned short* __restrict__ Yb, const unsigned short* __restrict__ RXb,
    const unsigned short* __restrict__ Xb, const unsigned short* __restrict__ Wt,
    const float* __restrict__ gb, unsigned short* __restrict__ OUTb,
    float* __restrict__ TS, int rowoff) {
  __shared__ __align__(16) unsigned short As[128 * kBK];  // 8 KB
  __shared__ __align__(16) unsigned short Bs[128 * kBK];  // 8 KB
  const int tid = threadIdx.x;
  const int lane = tid & 63, wv = tid >> 6;  // 8 waves
  const int ml = lane & 15, qd = lane >> 4;
  const int m0 = blockIdx.y * 128, n0 = blockIdx.x * 128;
  const int mw0 = (wv & 3) * 32, nw0 = (wv >> 2) * 64;
  const size_t ld = (size_t)kD * 2;
  const size_t DD = (size_t)kD * kD;
  f32x4 accH[2][4], accZ[2][4];
#pragma unroll
  for (int i = 0; i < 2; ++i)
#pragma unroll
    for (int j = 0; j < 4; ++j) { accH[i][j] = (f32x4)0.f; accZ[i][j] = (f32x4)0.f; }
  const unsigned short* Ap[4] = {Yb, RXb, Yb, Xb};
  const int wsel[4] = {4, 5, 2, 3};
  for (int p = 0; p < 4; ++p) {
    const char* Ab = (const char*)Ap[p] + (size_t)m0 * ld;
    const char* Bb = (const char*)(Wt + (size_t)wsel[p] * DD) + (size_t)n0 * ld;
    f32x4 (*acc)[4] = (p < 2) ? accH : accZ;
    for (int k0 = 0; k0 < kD; k0 += kBK) {
      {  // A + B: 8 chunks each / 8 waves
        int fb = wv * 1024 + lane * 16;
        size_t go = (size_t)(fb >> 6) * ld + (fb & 63) + (size_t)k0 * 2;
        gl_lds16(Ab + go, (char*)As + wv * 1024);
        gl_lds16(Bb + go, (char*)Bs + wv * 1024);
      }
      __syncthreads();
      bf16x8 af[2], bfr[4];
#pragma unroll
      for (int i = 0; i < 2; ++i)
        af[i] = *(const bf16x8*)(As + (mw0 + i * 16 + ml) * kBK + qd * 8);
#pragma unroll
      for (int j = 0; j < 4; ++j)
        bfr[j] = *(const bf16x8*)(Bs + (nw0 + j * 16 + ml) * kBK + qd * 8);
#pragma unroll
      for (int i = 0; i < 2; ++i)
#pragma unroll
        for (int j = 0; j < 4; ++j)
          acc[i][j] = __builtin_amdgcn_mfma_f32_16x16x32_bf16(af[i], bfr[j], acc[i][j], 0, 0, 0);
      __syncthreads();
    }
  }
#pragma unroll
  for (int i = 0; i < 2; ++i)
#pragma unroll
    for (int j = 0; j < 4; ++j)
#pragma unroll
      for (int r = 0; r < 4; ++r) {
        int m = m0 + mw0 + i * 16 + qd * 4 + r;
        int n = n0 + nw0 + j * 16 + ml;
        float z = sigmoidf_(accZ[i][j][r] + gb[2 * kD + n] + gb[3 * kD + n] - kBG);
        float hc = tanhf(accH[i][j][r] + gb[4 * kD + n] + gb[5 * kD + n]);
        size_t idx = (size_t)m * kD + n;
        float val = (1.0f - z) * b2f(Xb[idx]) + z * hc;
        if (POOL) {
          int b = (rowoff + m) & (kB - 1);
          atomicAdd(TS + (size_t)b * kD + n, val * (1.0f / kT));
        } else {
          OUTb[idx] = bf16u(val);
        }
      }
}

// -------- Positional embedding projection ----------
__global__ __launch_bounds__(64) void posp_kernel(const float* __restrict__ Wp,
                                                  float* __restrict__ P) {
  __shared__ float emb[512];
  int jj = blockIdx.x;
  int t = threadIdx.x;
  float pos = (float)(kJ - 1 - jj);
#pragma unroll
  for (int r = 0; r < 8; ++r) {
    int d = t + r * 64;
    int i = (d < 256) ? d : d - 256;
    float invf = expf(-((float)(2 * i) * (1.0f / 512.0f)) * 9.210340371976184f);
    float si = pos * invf;
    emb[d] = (d < 256) ? sinf(si) : cosf(si);
  }
  __syncthreads();
  float acc = 0.f;
  for (int d = 0; d < 512; ++d) acc = fmaf(emb[d], Wp[d * 64 + t], acc);
  P[jj * 64 + t] = acc;
}

// -------- Attention (fp32 math), KV bf16 in, AV out as bf16 ----------
__global__ __launch_bounds__(128) void attn_kernel(
    const float* __restrict__ Q, const unsigned short* __restrict__ KV,
    const float* __restrict__ P, const float* __restrict__ U,
    const float* __restrict__ V, unsigned short* __restrict__ AV) {
  __shared__ float ks[kJ][32];
  __shared__ float vs[kJ][32];
  __shared__ float ps[32][kJ + 2];
  const int b = blockIdx.x, h = blockIdx.y;
  const int tid = threadIdx.x;
  for (int idx = tid; idx < kJ * 8; idx += 128) {
    int j = idx >> 3, seg = idx & 7;
    const unsigned short* src = KV + ((size_t)(j * kB + b)) * 128 + h * 32 + seg * 4;
    us4 kq = *(const us4*)src;
    us4 vq = *(const us4*)(src + 64);
#pragma unroll
    for (int e = 0; e < 4; ++e) {
      ks[j][seg * 4 + e] = b2f(kq[e]);
      vs[j][seg * 4 + e] = b2f(vq[e]);
    }
  }
  for (int idx = tid; idx < kJ * 8; idx += 128) {
    int j = idx >> 3, seg = idx & 7;
    float4 pq = *(const float4*)(P + j * 64 + h * 32 + seg * 4);
    ps[seg * 4 + 0][j] = pq.x;
    ps[seg * 4 + 1][j] = pq.y;
    ps[seg * 4 + 2][j] = pq.z;
    ps[seg * 4 + 3][j] = pq.w;
  }
  __syncthreads();
  const int i = tid;
  float qu[32], qv[32];
  const float* qp = Q + ((size_t)(i * kB + b)) * 64 + h * 32;
#pragma unroll
  for (int d = 0; d < 32; ++d) {
    float qd = qp[d];
    qu[d] = qd + U[h * 32 + d];
    qv[d] = qd + V[h * 32 + d];
  }
  float m = -INFINITY, l = 0.f, acc[32] = {};
  const float scale = 0.17677669529663687f;
  for (int j = 0; j <= i + kM; ++j) {
    float s = 0.f;
#pragma unroll
    for (int d = 0; d < 32; d += 4) {
      float4 k4 = *(const float4*)&ks[j][d];
      s = fmaf(qu[d + 0], k4.x, s);
      s = fmaf(qu[d + 1], k4.y, s);
      s = fmaf(qu[d + 2], k4.z, s);
      s = fmaf(qu[d + 3], k4.w, s);
    }
    int jj = j + (kT - 1) - i;
#pragma unroll
    for (int d = 0; d < 32; ++d) s = fmaf(qv[d], ps[d][jj], s);
    float ls = s * scale;
    float nm = fmaxf(m, ls);
    float w = __expf(ls - nm);
    float f = __expf(m - nm);
    l = l * f + w;
#pragma unroll
    for (int d = 0; d < 32; d += 4) {
      float4 v4 = *(const float4*)&vs[j][d];
      acc[d + 0] = fmaf(acc[d + 0], f, w * v4.x);
      acc[d + 1] = fmaf(acc[d + 1], f, w * v4.y);
      acc[d + 2] = fmaf(acc[d + 2], f, w * v4.z);
      acc[d + 3] = fmaf(acc[d + 3], f, w * v4.w);
    }
    m = nm;
  }
  float inv = 1.0f / l;
  unsigned short* o = AV + ((size_t)(i * kB + b)) * 64 + h * 32;
#pragma unroll
  for (int d = 0; d < 32; ++d) o[d] = bf16u(acc[d] * inv);
}

// -------- fp32 fallback GEMM for the small critic head --------
template <int ACTF, bool DUAL>
__global__ __launch_bounds__(256) void gemm_kernel(
    const float* __restrict__ A1, const float* __restrict__ Bm1, int K1,
    const float* __restrict__ A2, const float* __restrict__ Bm2, int K2,
    const float* __restrict__ bias, float* __restrict__ C, int Mrows, int N) {
  __shared__ float As[16][68];
  __shared__ float Bs[16][68];
  const int tid = threadIdx.x;
  const int tx = tid & 15, ty = tid >> 4;
  const int m0 = blockIdx.y * 64, n0 = blockIdx.x * 64;
  const int ar = tid >> 2, aseg = tid & 3;
  float acc[4][4] = {};
#pragma unroll
  for (int pass = 0; pass < (DUAL ? 2 : 1); ++pass) {
    const float* A = (DUAL && pass) ? A2 : A1;
    const float* Bm = (DUAL && pass) ? Bm2 : Bm1;
    const int K = (DUAL && pass) ? K2 : K1;
    for (int k0 = 0; k0 < K; k0 += 16) {
      {
        int row = m0 + ar;
        int kb = k0 + aseg * 4;
        float x0 = 0.f, x1 = 0.f, x2 = 0.f, x3 = 0.f;
        if (row < Mrows) {
          const float* ap = A + (size_t)row * K + kb;
          if (kb + 3 < K) {
            float4 t = *(const float4*)ap;
            x0 = t.x; x1 = t.y; x2 = t.z; x3 = t.w;
          } else {
            if (kb + 0 < K) x0 = ap[0];
            if (kb + 1 < K) x1 = ap[1];
            if (kb + 2 < K) x2 = ap[2];
          }
        }
        As[aseg * 4 + 0][ar] = x0;
        As[aseg * 4 + 1][ar] = x1;
        As[aseg * 4 + 2][ar] = x2;
        As[aseg * 4 + 3][ar] = x3;
      }
      {
        int krow = k0 + ty;
        int nb = n0 + tx * 4;
        float y0 = 0.f, y1 = 0.f, y2 = 0.f, y3 = 0.f;
        if (krow < K) {
          const float* bp = Bm + (size_t)krow * N + nb;
          if (nb + 3 < N) {
            float4 t = *(const float4*)bp;
            y0 = t.x; y1 = t.y; y2 = t.z; y3 = t.w;
          } else {
            if (nb + 0 < N) y0 = bp[0];
            if (nb + 1 < N) y1 = bp[1];
            if (nb + 2 < N) y2 = bp[2];
          }
        }
        *(float4*)&Bs[ty][tx * 4] = make_float4(y0, y1, y2, y3);
      }
      __syncthreads();
#pragma unroll
      for (int kk = 0; kk < 16; ++kk) {
        float a[4], bb[4];
        *(float4*)a = *(const float4*)&As[kk][ty * 4];
        *(float4*)bb = *(const float4*)&Bs[kk][tx * 4];
#pragma unroll
        for (int i = 0; i < 4; ++i)
#pragma unroll
          for (int j = 0; j < 4; ++j) acc[i][j] = fmaf(a[i], bb[j], acc[i][j]);
      }
      __syncthreads();
    }
  }
#pragma unroll
  for (int i = 0; i < 4; ++i) {
    int m = m0 + ty * 4 + i;
    if (m >= Mrows) continue;
#pragma unroll
    for (int j = 0; j < 4; ++j) {
      int n = n0 + tx * 4 + j;
      if (n >= N) continue;
      float val = acc[i][j];
      if (bias) val += bias[n];
      if (ACTF == 1) val = fmaxf(val, 0.f);
      C[(size_t)m * N + n] = val;
    }
  }
}

}  // namespace

extern "C" void kernel_launch(void* const* d_in, const int* in_sizes, int n_in,
                              void* d_out, int out_size, void* d_ws, size_t ws_size,
                              hipStream_t stream) {
  (void)in_sizes; (void)n_in; (void)out_size;
  const float* aug    = (const float*)d_in[0];
  const float* action = (const float*)d_in[1];
  const float* memory = (const float*)d_in[2];
  const float* W_q    = (const float*)d_in[3];
  const float* W_kv   = (const float*)d_in[4];
  const float* W_p    = (const float*)d_in[5];
  const float* W_out  = (const float*)d_in[6];
  const float* u      = (const float*)d_in[7];
  const float* v      = (const float*)d_in[8];
  const float* ln1_g  = (const float*)d_in[9];
  const float* ln1_b  = (const float*)d_in[10];
  const float* ln2_g  = (const float*)d_in[11];
  const float* ln2_b  = (const float*)d_in[12];
  const float* ff_W1  = (const float*)d_in[13];
  const float* ff_b1  = (const float*)d_in[14];
  const float* ff_W2  = (const float*)d_in[15];
  const float* ff_b2  = (const float*)d_in[16];
  const float* g1_W   = (const float*)d_in[17];
  const float* g1_b   = (const float*)d_in[18];
  const float* g2_W   = (const float*)d_in[19];
  const float* g2_b   = (const float*)d_in[20];
  const float* d1_W   = (const float*)d_in[21];
  const float* d1_b   = (const float*)d_in[22];
  const float* d2_W   = (const float*)d_in[23];
  const float* d2_b   = (const float*)d_in[24];
  const float* d3_W   = (const float*)d_in[25];
  const float* d3_b   = (const float*)d_in[26];
  const float* d4_W   = (const float*)d_in[27];
  const float* d4_b   = (const float*)d_in[28];
  float* out = (float*)d_out;

  // ---------------- workspace carve ----------------
  char* base = (char*)d_ws;
  auto alloc = [&](size_t bytes) -> char* {
    char* p = base;
    base += (bytes + 255) & ~(size_t)255;
    return p;
  };
  unsigned short* Wqt  = (unsigned short*)alloc((size_t)64 * 512 * 2);
  unsigned short* Wkvt = (unsigned short*)alloc((size_t)128 * 512 * 2);
  unsigned short* Wot  = (unsigned short*)alloc((size_t)512 * 64 * 2);
  unsigned short* Wf1t = (unsigned short*)alloc((size_t)64 * 512 * 2);
  unsigned short* Wf2t = (unsigned short*)alloc((size_t)512 * 64 * 2);
  unsigned short* G1t  = (unsigned short*)alloc((size_t)6 * 512 * 512 * 2);
  unsigned short* G2t  = (unsigned short*)alloc((size_t)6 * 512 * 512 * 2);
  unsigned short* Memb = (unsigned short*)alloc((size_t)3072 * 512 * 2);
  unsigned short* KVb  = (unsigned short*)alloc((size_t)kJ * kB * 128 * 2);
  float* Qb  = (float*)alloc((size_t)kTB * 64 * 4);
  unsigned short* AVb = (unsigned short*)alloc((size_t)kTB * 64 * 2);
  unsigned short* Xb  = (unsigned short*)alloc((size_t)kTB * kD * 2);  // raw aug bf16
  float* Pb  = (float*)alloc((size_t)kJ * 64 * 4);
  float* TSb = (float*)alloc((size_t)kB * kD * 4);
  float* H1b = (float*)alloc((size_t)kB * 1024 * 4);
  float* H2b = (float*)alloc((size_t)kB * 512 * 4);
  float* H3b = (float*)alloc((size_t)kB * 320 * 4);
  size_t fixedBytes = (size_t)(base - (char*)d_ws);
  const size_t ln1Bytes = (size_t)kTB * kD * 2;  // L1b overlaps chunk region
  int nch = 1;
  while (nch < 32) {
    size_t chunkBytes = (size_t)(kTB / nch) * 4224 + 4096;
    size_t reuse = chunkBytes > ln1Bytes ? chunkBytes : ln1Bytes;
    if (fixedBytes + reuse <= ws_size) break;
    nch <<= 1;
  }
  const int CR = kTB / nch;
  char* R = base;
  unsigned short* L1b = (unsigned short*)R;  // ln1(aug) bf16 (dead before chunks)
  char* rp = R;
  auto ralloc = [&](size_t bytes) -> char* {
    char* p = rp;
    rp += (bytes + 255) & ~(size_t)255;
    return p;
  };
  unsigned short* Ycb   = (unsigned short*)ralloc((size_t)CR * 512 * 2);
  unsigned short* RXcb  = (unsigned short*)ralloc((size_t)CR * 512 * 2);
  unsigned short* SRCcb = (unsigned short*)ralloc((size_t)CR * 512 * 2);
  unsigned short* LN2cb = (unsigned short*)ralloc((size_t)CR * 512 * 2);
  unsigned short* F1cb  = (unsigned short*)ralloc((size_t)CR * 64 * 2);

  const float* np = nullptr;

  // -------- prep --------
  hipMemsetAsync(TSb, 0, (size_t)kB * kD * sizeof(float), stream);
  transp_kernel<<<dim3(2, 16, 1), 256, 0, stream>>>(W_q, Wqt, 512, 64);
  transp_kernel<<<dim3(4, 16, 1), 256, 0, stream>>>(W_kv, Wkvt, 512, 128);
  transp_kernel<<<dim3(16, 2, 1), 256, 0, stream>>>(W_out, Wot, 64, 512);
  transp_kernel<<<dim3(2, 16, 1), 256, 0, stream>>>(ff_W1, Wf1t, 512, 64);
  transp_kernel<<<dim3(16, 2, 1), 256, 0, stream>>>(ff_W2, Wf2t, 64, 512);
  transp_kernel<<<dim3(16, 16, 6), 256, 0, stream>>>(g1_W, G1t, 512, 512);
  transp_kernel<<<dim3(16, 16, 6), 256, 0, stream>>>(g2_W, G2t, 512, 512);
  conv_bf16_kernel<<<(3072 * 512 / 8 + 255) / 256, 256, 0, stream>>>(
      memory, Memb, (size_t)3072 * 512);
  // ln1(aug) -> L1b bf16 and raw aug -> Xb bf16 (one fp32 read)
  ln1_dual_kernel<<<kTB / 4, 256, 0, stream>>>(aug, ln1_g, ln1_b, L1b, Xb, kTB);
  // kv = [memory; ln1] @ W_kv  (bf16 out)
  mfma_gemm_bt<128, 1><<<dim3(1, 3072 / 128), 256, 0, stream>>>(
      Memb, Wkvt, 512, np, KVb, 128);
  mfma_gemm_bt<128, 1><<<dim3(1, kTB / 128), 256, 0, stream>>>(
      L1b, Wkvt, 512, np, KVb + (size_t)3072 * 128, 128);
  // q = ln1 @ W_q (fp32 out)
  mfma_gemm_bt<64, 0><<<dim3(1, kTB / 128), 256, 0, stream>>>(
      L1b, Wqt, 512, np, Qb, 64);
  posp_kernel<<<kJ, 64, 0, stream>>>(W_p, Pb);
  attn_kernel<<<dim3(kB, kH), 128, 0, stream>>>(Qb, KVb, Pb, u, v, AVb);

  for (int c = 0; c < nch; ++c) {
    const int R0 = c * CR;
    const unsigned short* Xc = Xb + (size_t)R0 * kD;
    // y1 = av @ W_out (bf16 out)
    mfma_gemm_bt<128, 1><<<dim3(4, CR / 128), 256, 0, stream>>>(
        AVb + (size_t)R0 * 64, Wot, 64, np, Ycb, 512);
    // gate1
    mfma_gate_r<<<dim3(2, CR / 128), 512, 0, stream>>>(Ycb, Xc, G1t, g1_b, RXcb);
    mfma_gate_hz<false><<<dim3(4, CR / 128), 512, 0, stream>>>(
        Ycb, RXcb, Xc, G1t, g1_b, SRCcb, nullptr, R0);
    // ln2 (bf16 in/out)
    ln_b16_kernel<<<CR / 4, 256, 0, stream>>>(SRCcb, ln2_g, ln2_b, LN2cb, CR);
    // ff1 = relu(ln2 @ ff_W1 + b1) (bf16 out)
    mfma_gemm_bt<64, 2><<<dim3(1, CR / 128), 256, 0, stream>>>(
        LN2cb, Wf1t, 512, ff_b1, F1cb, 64);
    // y2 = ff1 @ ff_W2 + b2 (bf16 out)
    mfma_gemm_bt<128, 3><<<dim3(4, CR / 128), 256, 0, stream>>>(
        F1cb, Wf2t, 64, ff_b2, Ycb, 512);
    // gate2 + fused mean-pool
    mfma_gate_r<<<dim3(2, CR / 128), 512, 0, stream>>>(Ycb, SRCcb, G2t, g2_b, RXcb);
    mfma_gate_hz<true><<<dim3(4, CR / 128), 512, 0, stream>>>(
        Ycb, RXcb, SRCcb, G2t, g2_b, nullptr, TSb, R0);
  }

  // critic head (fp32)
  gemm_kernel<1, false><<<dim3(16, kB / 64), 256, 0, stream>>>(
      TSb, d1_W, 512, np, np, 0, d1_b, H1b, kB, 1024);
  gemm_kernel<1, true><<<dim3(8, kB / 64), 256, 0, stream>>>(
      H1b, d2_W, 1024, action, d2_W + (size_t)1024 * 512, 64, d2_b, H2b, kB, 512);
  gemm_kernel<1, false><<<dim3(5, kB / 64), 256, 0, stream>>>(
      H2b, d3_W, 512, np, np, 0, d3_b, H3b, kB, 300);
  gemm_kernel<1, false><<<dim3(1, kB / 64), 256, 0, stream>>>(
      H3b, d4_W, 300, np, np, 0, d4_b, out, kB, 1);
}

// Round 7
// 1522.134 us; speedup vs baseline: 1.4005x; 1.0115x over previous
//
#include <hip/hip_runtime.h>
#include <math.h>

namespace {

constexpr int kT = 128, kB = 512, kD = 512, kM = 6, kH = 2;
constexpr int kJ = kT + kM;          // 134
constexpr float kBG = 0.1f;
constexpr int kTB = kT * kB;         // 65536 rows
constexpr int kBK = 32;              // K-tile for MFMA kernels

typedef __attribute__((ext_vector_type(8))) short bf16x8;
typedef __attribute__((ext_vector_type(4))) float f32x4;
typedef __attribute__((ext_vector_type(8))) unsigned short us8;
typedef __attribute__((ext_vector_type(4))) unsigned short us4;

__device__ __forceinline__ float sigmoidf_(float x) {
  return 1.0f / (1.0f + __expf(-x));
}

__device__ __forceinline__ unsigned short bf16u(float f) {
  union { float f; unsigned u; } c; c.f = f;
  unsigned r = c.u + 0x7fffu + ((c.u >> 16) & 1u);
  return (unsigned short)(r >> 16);
}

__device__ __forceinline__ float b2f(unsigned short u) {
  union { unsigned u; float f; } c; c.u = (unsigned)u << 16;
  return c.f;
}

__device__ __forceinline__ void gl_lds16(const void* g, void* l) {
  __builtin_amdgcn_global_load_lds(
      (const __attribute__((address_space(1))) unsigned int*)g,
      (__attribute__((address_space(3))) unsigned int*)l, 16, 0, 0);
}

// ---- transpose + cast: W fp32 [K][N] -> Wt bf16 [N][K]; dims mult of 32 ----
__global__ __launch_bounds__(256) void transp_kernel(const float* __restrict__ W,
                                                     unsigned short* __restrict__ Wt,
                                                     int K, int N) {
  __shared__ float t[32][33];
  const int n0 = blockIdx.x * 32, k0 = blockIdx.y * 32;
  const float* Wb = W + (size_t)blockIdx.z * K * N;
  unsigned short* Wtb = Wt + (size_t)blockIdx.z * K * N;
  int tx = threadIdx.x & 31, ty = threadIdx.x >> 5;  // 32 x 8
#pragma unroll
  for (int r = 0; r < 32; r += 8)
    t[ty + r][tx] = Wb[(size_t)(k0 + ty + r) * N + n0 + tx];
  __syncthreads();
#pragma unroll
  for (int r = 0; r < 32; r += 8)
    Wtb[(size_t)(n0 + ty + r) * K + k0 + tx] = bf16u(t[tx][ty + r]);
}

// ---- fp32 -> bf16 elementwise (n multiple of 8) ----
__global__ __launch_bounds__(256) void conv_bf16_kernel(const float* __restrict__ in,
                                                        unsigned short* __restrict__ outb,
                                                        size_t n) {
  size_t idx = ((size_t)blockIdx.x * 256 + threadIdx.x) * 8;
  if (idx >= n) return;
  float4 a = *(const float4*)(in + idx);
  float4 c = *(const float4*)(in + idx + 4);
  us8 o;
  o[0] = bf16u(a.x); o[1] = bf16u(a.y); o[2] = bf16u(a.z); o[3] = bf16u(a.w);
  o[4] = bf16u(c.x); o[5] = bf16u(c.y); o[6] = bf16u(c.z); o[7] = bf16u(c.w);
  *(us8*)(outb + idx) = o;
}

// ---- LN1 dual-output: LN(x) -> bf16 AND raw x -> bf16, one fp32 read ----
__global__ __launch_bounds__(256) void ln1_dual_kernel(const float* __restrict__ in,
                                                       const float* __restrict__ g,
                                                       const float* __restrict__ b,
                                                       unsigned short* __restrict__ outLN,
                                                       unsigned short* __restrict__ outRaw,
                                                       int nrows) {
  int wave = threadIdx.x >> 6, lane = threadIdx.x & 63;
  int row = blockIdx.x * 4 + wave;
  if (row >= nrows) return;
  const float* p = in + (size_t)row * kD + lane * 8;
  float4 a = *(const float4*)p;
  float4 c = *(const float4*)(p + 4);
  float v[8] = {a.x, a.y, a.z, a.w, c.x, c.y, c.z, c.w};
  float s = 0.f;
#pragma unroll
  for (int i = 0; i < 8; ++i) s += v[i];
#pragma unroll
  for (int off = 32; off; off >>= 1) s += __shfl_xor(s, off);
  float mu = s * (1.0f / 512.0f);
  float q = 0.f;
#pragma unroll
  for (int i = 0; i < 8; ++i) { float d = v[i] - mu; q += d * d; }
#pragma unroll
  for (int off = 32; off; off >>= 1) q += __shfl_xor(q, off);
  float rstd = rsqrtf(q * (1.0f / 512.0f) + 1e-5f);
  us8 oln, oraw;
#pragma unroll
  for (int i = 0; i < 8; ++i) {
    int col = lane * 8 + i;
    oln[i] = bf16u((v[i] - mu) * rstd * g[col] + b[col]);
    oraw[i] = bf16u(v[i]);
  }
  size_t off8 = (size_t)row * kD + lane * 8;
  *(us8*)(outLN + off8) = oln;
  *(us8*)(outRaw + off8) = oraw;
}

// ---- LN with bf16 input -> bf16 out ----
__global__ __launch_bounds__(256) void ln_b16_kernel(const unsigned short* __restrict__ in,
                                                     const float* __restrict__ g,
                                                     const float* __restrict__ b,
                                                     unsigned short* __restrict__ outb,
                                                     int nrows) {
  int wave = threadIdx.x >> 6, lane = threadIdx.x & 63;
  int row = blockIdx.x * 4 + wave;
  if (row >= nrows) return;
  us8 iv = *(const us8*)(in + (size_t)row * kD + lane * 8);
  float v[8];
#pragma unroll
  for (int i = 0; i < 8; ++i) v[i] = b2f(iv[i]);
  float s = 0.f;
#pragma unroll
  for (int i = 0; i < 8; ++i) s += v[i];
#pragma unroll
  for (int off = 32; off; off >>= 1) s += __shfl_xor(s, off);
  float mu = s * (1.0f / 512.0f);
  float q = 0.f;
#pragma unroll
  for (int i = 0; i < 8; ++i) { float d = v[i] - mu; q += d * d; }
#pragma unroll
  for (int off = 32; off; off >>= 1) q += __shfl_xor(q, off);
  float rstd = rsqrtf(q * (1.0f / 512.0f) + 1e-5f);
  us8 o;
#pragma unroll
  for (int i = 0; i < 8; ++i) {
    int col = lane * 8 + i;
    o[i] = bf16u((v[i] - mu) * rstd * g[col] + b[col]);
  }
  *(us8*)(outb + (size_t)row * kD + lane * 8) = o;
}

// ============ MFMA GEMM, B^T input: C[M][N] = A[M][K] @ Bt[N][K]^T ==========
// 128 x TN tile, 256 threads (4 waves), BK=32, global_load_lds width 16.
// EPI: 0 = fp32 out, 1 = bf16 out, 2 = bias+relu+bf16, 3 = bias+bf16.
template <int TN, int EPI>
__global__ __launch_bounds__(256) void mfma_gemm_bt(
    const unsigned short* __restrict__ A, const unsigned short* __restrict__ Bt,
    int K, const float* __restrict__ bias, void* __restrict__ Cv, int N) {
  constexpr int MI = (TN == 128) ? 4 : 2;
  constexpr int NJ = 4;
  constexpr int BCH = TN * 64 / 1024;
  __shared__ __align__(16) unsigned short As[128 * kBK];
  __shared__ __align__(16) unsigned short Bs[TN * kBK];
  const int tid = threadIdx.x;
  const int lane = tid & 63, wv = tid >> 6;
  const int ml = lane & 15, qd = lane >> 4;
  const int m0 = blockIdx.y * 128, n0 = blockIdx.x * TN;
  const int mw0 = (TN == 128) ? (wv >> 1) * 64 : wv * 32;
  const int nw0 = (TN == 128) ? (wv & 1) * 64 : 0;
  const size_t ldA = (size_t)K * 2, ldB = (size_t)K * 2;
  const char* Ab = (const char*)A + (size_t)m0 * ldA;
  const char* Bb = (const char*)Bt + (size_t)n0 * ldB;
  f32x4 acc[MI][NJ];
#pragma unroll
  for (int i = 0; i < MI; ++i)
#pragma unroll
    for (int j = 0; j < NJ; ++j) acc[i][j] = (f32x4)0.f;
  for (int k0 = 0; k0 < K; k0 += kBK) {
#pragma unroll
    for (int c = wv; c < 8; c += 4) {
      int fb = c * 1024 + lane * 16;
      gl_lds16(Ab + (size_t)(fb >> 6) * ldA + (fb & 63) + (size_t)k0 * 2,
               (char*)As + c * 1024);
    }
#pragma unroll
    for (int c = wv; c < BCH; c += 4) {
      int fb = c * 1024 + lane * 16;
      gl_lds16(Bb + (size_t)(fb >> 6) * ldB + (fb & 63) + (size_t)k0 * 2,
               (char*)Bs + c * 1024);
    }
    __syncthreads();
    bf16x8 af[MI], bfr[NJ];
#pragma unroll
    for (int i = 0; i < MI; ++i)
      af[i] = *(const bf16x8*)(As + (mw0 + i * 16 + ml) * kBK + qd * 8);
#pragma unroll
    for (int j = 0; j < NJ; ++j)
      bfr[j] = *(const bf16x8*)(Bs + (nw0 + j * 16 + ml) * kBK + qd * 8);
#pragma unroll
    for (int i = 0; i < MI; ++i)
#pragma unroll
      for (int j = 0; j < NJ; ++j)
        acc[i][j] = __builtin_amdgcn_mfma_f32_16x16x32_bf16(af[i], bfr[j], acc[i][j], 0, 0, 0);
    __syncthreads();
  }
#pragma unroll
  for (int i = 0; i < MI; ++i)
#pragma unroll
    for (int j = 0; j < NJ; ++j)
#pragma unroll
      for (int r = 0; r < 4; ++r) {
        int m = m0 + mw0 + i * 16 + qd * 4 + r;
        int n = n0 + nw0 + j * 16 + ml;
        float val = acc[i][j][r];
        if (EPI >= 2) val += bias[n];
        if (EPI == 2) val = fmaxf(val, 0.f);
        size_t idx = (size_t)m * N + n;
        if (EPI == 0) ((float*)Cv)[idx] = val;
        else ((unsigned short*)Cv)[idx] = bf16u(val);
      }
}

// XCD swizzle: 1-D grid of MG*NB blocks. All NB n-blocks of one m-group land
// on the SAME XCD in ADJACENT dispatch slots -> A tile fetched once into that
// XCD's L2 and shared (perf-only heuristic; correctness never depends on it).
template <int NBLOG>
__device__ __forceinline__ void xcd_decode(int& m0, int& n0, int tileN) {
  const int L = blockIdx.x;
  const int xcd = L & 7;
  const int s = L >> 3;
  const int mgPerX = (int)(gridDim.x >> (3 + NBLOG));
  const int mg = xcd * mgPerX + (s >> NBLOG);
  const int nb = s & ((1 << NBLOG) - 1);
  m0 = mg * 128;
  n0 = nb * tileN;
}

// ====== gate r: 128x256 tile, 512 threads (8 waves, 2M x 4N), per-wave 64x64.
// acc = 16 f32x4 = 64 AGPR; ~128 total regs -> 4 waves/SIMD (50% occ).
// acc = Y@W0t^T + X@W1t^T ; RX = bf16(sigmoid(acc+b0+b1)*x)
__global__ __launch_bounds__(512, 4) void mfma_gate_r(
    const unsigned short* __restrict__ Yb, const unsigned short* __restrict__ Xb,
    const unsigned short* __restrict__ Wt, const float* __restrict__ gb,
    unsigned short* __restrict__ RX) {
  __shared__ __align__(16) unsigned short As[128 * kBK];   // 8 KB
  __shared__ __align__(16) unsigned short Bs[256 * kBK];   // 16 KB
  const int tid = threadIdx.x;
  const int lane = tid & 63, wv = tid >> 6;  // 8 waves
  const int ml = lane & 15, qd = lane >> 4;
  int m0, n0;
  xcd_decode<1>(m0, n0, 256);
  const int mw0 = (wv & 1) * 64, nw0 = (wv >> 1) * 64;
  const size_t ld = (size_t)kD * 2;
  f32x4 acc[4][4];
#pragma unroll
  for (int i = 0; i < 4; ++i)
#pragma unroll
    for (int j = 0; j < 4; ++j) acc[i][j] = (f32x4)0.f;
  for (int p = 0; p < 2; ++p) {
    const char* Ab = (const char*)(p ? Xb : Yb) + (size_t)m0 * ld;
    const char* Bb = (const char*)(Wt + (size_t)p * kD * kD) + (size_t)n0 * ld;
    for (int k0 = 0; k0 < kD; k0 += kBK) {
      {  // A: 8 chunks / 8 waves
        int fb = wv * 1024 + lane * 16;
        gl_lds16(Ab + (size_t)(fb >> 6) * ld + (fb & 63) + (size_t)k0 * 2,
                 (char*)As + wv * 1024);
      }
#pragma unroll
      for (int c = wv; c < 16; c += 8) {  // B: 16 chunks / 8 waves
        int fb = c * 1024 + lane * 16;
        gl_lds16(Bb + (size_t)(fb >> 6) * ld + (fb & 63) + (size_t)k0 * 2,
                 (char*)Bs + c * 1024);
      }
      __syncthreads();
      bf16x8 af[4], bfr[4];
#pragma unroll
      for (int i = 0; i < 4; ++i)
        af[i] = *(const bf16x8*)(As + (mw0 + i * 16 + ml) * kBK + qd * 8);
#pragma unroll
      for (int j = 0; j < 4; ++j)
        bfr[j] = *(const bf16x8*)(Bs + (nw0 + j * 16 + ml) * kBK + qd * 8);
#pragma unroll
      for (int i = 0; i < 4; ++i)
#pragma unroll
        for (int j = 0; j < 4; ++j)
          acc[i][j] = __builtin_amdgcn_mfma_f32_16x16x32_bf16(af[i], bfr[j], acc[i][j], 0, 0, 0);
      __syncthreads();
    }
  }
#pragma unroll
  for (int i = 0; i < 4; ++i)
#pragma unroll
    for (int j = 0; j < 4; ++j)
#pragma unroll
      for (int r = 0; r < 4; ++r) {
        int m = m0 + mw0 + i * 16 + qd * 4 + r;
        int n = n0 + nw0 + j * 16 + ml;
        float rg = sigmoidf_(acc[i][j][r] + gb[n] + gb[kD + n]);
        size_t idx = (size_t)m * kD + n;
        RX[idx] = bf16u(rg * b2f(Xb[idx]));
      }
}

// ====== gate h+z: 128x128 tile, 512 threads (8 waves, 4M x 2N), per-wave
// 32x64; accH+accZ = 2 x 8 f32x4 = 64 AGPR -> 4 waves/SIMD (50% occ).
// accH = Y@W4 + RX@W5 ; accZ = Y@W2 + X@W3 (4 sequential passes).
// out = (1-z)*x + z*tanh(accH+b4+b5), z = sigmoid(accZ+b2+b3-BG), x bf16.
// POOL=false: OUTb bf16. POOL=true: atomic mean-pool into TS.
template <bool POOL>
__global__ __launch_bounds__(512, 4) void mfma_gate_hz(
    const unsigned short* __restrict__ Yb, const unsigned short* __restrict__ RXb,
    const unsigned short* __restrict__ Xb, const unsigned short* __restrict__ Wt,
    const float* __restrict__ gb, unsigned short* __restrict__ OUTb,
    float* __restrict__ TS, int rowoff) {
  __shared__ __align__(16) unsigned short As[128 * kBK];  // 8 KB
  __shared__ __align__(16) unsigned short Bs[128 * kBK];  // 8 KB
  const int tid = threadIdx.x;
  const int lane = tid & 63, wv = tid >> 6;  // 8 waves
  const int ml = lane & 15, qd = lane >> 4;
  int m0, n0;
  xcd_decode<2>(m0, n0, 128);
  const int mw0 = (wv & 3) * 32, nw0 = (wv >> 2) * 64;
  const size_t ld = (size_t)kD * 2;
  const size_t DD = (size_t)kD * kD;
  f32x4 accH[2][4], accZ[2][4];
#pragma unroll
  for (int i = 0; i < 2; ++i)
#pragma unroll
    for (int j = 0; j < 4; ++j) { accH[i][j] = (f32x4)0.f; accZ[i][j] = (f32x4)0.f; }
  const unsigned short* Ap[4] = {Yb, RXb, Yb, Xb};
  const int wsel[4] = {4, 5, 2, 3};
  for (int p = 0; p < 4; ++p) {
    const char* Ab = (const char*)Ap[p] + (size_t)m0 * ld;
    const char* Bb = (const char*)(Wt + (size_t)wsel[p] * DD) + (size_t)n0 * ld;
    f32x4 (*acc)[4] = (p < 2) ? accH : accZ;
    for (int k0 = 0; k0 < kD; k0 += kBK) {
      {  // A + B: 8 chunks each / 8 waves
        int fb = wv * 1024 + lane * 16;
        size_t go = (size_t)(fb >> 6) * ld + (fb & 63) + (size_t)k0 * 2;
        gl_lds16(Ab + go, (char*)As + wv * 1024);
        gl_lds16(Bb + go, (char*)Bs + wv * 1024);
      }
      __syncthreads();
      bf16x8 af[2], bfr[4];
#pragma unroll
      for (int i = 0; i < 2; ++i)
        af[i] = *(const bf16x8*)(As + (mw0 + i * 16 + ml) * kBK + qd * 8);
#pragma unroll
      for (int j = 0; j < 4; ++j)
        bfr[j] = *(const bf16x8*)(Bs + (nw0 + j * 16 + ml) * kBK + qd * 8);
#pragma unroll
      for (int i = 0; i < 2; ++i)
#pragma unroll
        for (int j = 0; j < 4; ++j)
          acc[i][j] = __builtin_amdgcn_mfma_f32_16x16x32_bf16(af[i], bfr[j], acc[i][j], 0, 0, 0);
      __syncthreads();
    }
  }
#pragma unroll
  for (int i = 0; i < 2; ++i)
#pragma unroll
    for (int j = 0; j < 4; ++j)
#pragma unroll
      for (int r = 0; r < 4; ++r) {
        int m = m0 + mw0 + i * 16 + qd * 4 + r;
        int n = n0 + nw0 + j * 16 + ml;
        float z = sigmoidf_(accZ[i][j][r] + gb[2 * kD + n] + gb[3 * kD + n] - kBG);
        float hc = tanhf(accH[i][j][r] + gb[4 * kD + n] + gb[5 * kD + n]);
        size_t idx = (size_t)m * kD + n;
        float val = (1.0f - z) * b2f(Xb[idx]) + z * hc;
        if (POOL) {
          int b = (rowoff + m) & (kB - 1);
          atomicAdd(TS + (size_t)b * kD + n, val * (1.0f / kT));
        } else {
          OUTb[idx] = bf16u(val);
        }
      }
}

// -------- Positional embedding projection ----------
__global__ __launch_bounds__(64) void posp_kernel(const float* __restrict__ Wp,
                                                  float* __restrict__ P) {
  __shared__ float emb[512];
  int jj = blockIdx.x;
  int t = threadIdx.x;
  float pos = (float)(kJ - 1 - jj);
#pragma unroll
  for (int r = 0; r < 8; ++r) {
    int d = t + r * 64;
    int i = (d < 256) ? d : d - 256;
    float invf = expf(-((float)(2 * i) * (1.0f / 512.0f)) * 9.210340371976184f);
    float si = pos * invf;
    emb[d] = (d < 256) ? sinf(si) : cosf(si);
  }
  __syncthreads();
  float acc = 0.f;
  for (int d = 0; d < 512; ++d) acc = fmaf(emb[d], Wp[d * 64 + t], acc);
  P[jj * 64 + t] = acc;
}

// -------- Attention (fp32 math), KV bf16 in, AV out as bf16 ----------
__global__ __launch_bounds__(128) void attn_kernel(
    const float* __restrict__ Q, const unsigned short* __restrict__ KV,
    const float* __restrict__ P, const float* __restrict__ U,
    const float* __restrict__ V, unsigned short* __restrict__ AV) {
  __shared__ float ks[kJ][32];
  __shared__ float vs[kJ][32];
  __shared__ float ps[32][kJ + 2];
  const int b = blockIdx.x, h = blockIdx.y;
  const int tid = threadIdx.x;
  for (int idx = tid; idx < kJ * 8; idx += 128) {
    int j = idx >> 3, seg = idx & 7;
    const unsigned short* src = KV + ((size_t)(j * kB + b)) * 128 + h * 32 + seg * 4;
    us4 kq = *(const us4*)src;
    us4 vq = *(const us4*)(src + 64);
#pragma unroll
    for (int e = 0; e < 4; ++e) {
      ks[j][seg * 4 + e] = b2f(kq[e]);
      vs[j][seg * 4 + e] = b2f(vq[e]);
    }
  }
  for (int idx = tid; idx < kJ * 8; idx += 128) {
    int j = idx >> 3, seg = idx & 7;
    float4 pq = *(const float4*)(P + j * 64 + h * 32 + seg * 4);
    ps[seg * 4 + 0][j] = pq.x;
    ps[seg * 4 + 1][j] = pq.y;
    ps[seg * 4 + 2][j] = pq.z;
    ps[seg * 4 + 3][j] = pq.w;
  }
  __syncthreads();
  const int i = tid;
  float qu[32], qv[32];
  const float* qp = Q + ((size_t)(i * kB + b)) * 64 + h * 32;
#pragma unroll
  for (int d = 0; d < 32; ++d) {
    float qd = qp[d];
    qu[d] = qd + U[h * 32 + d];
    qv[d] = qd + V[h * 32 + d];
  }
  float m = -INFINITY, l = 0.f, acc[32] = {};
  const float scale = 0.17677669529663687f;
  for (int j = 0; j <= i + kM; ++j) {
    float s = 0.f;
#pragma unroll
    for (int d = 0; d < 32; d += 4) {
      float4 k4 = *(const float4*)&ks[j][d];
      s = fmaf(qu[d + 0], k4.x, s);
      s = fmaf(qu[d + 1], k4.y, s);
      s = fmaf(qu[d + 2], k4.z, s);
      s = fmaf(qu[d + 3], k4.w, s);
    }
    int jj = j + (kT - 1) - i;
#pragma unroll
    for (int d = 0; d < 32; ++d) s = fmaf(qv[d], ps[d][jj], s);
    float ls = s * scale;
    float nm = fmaxf(m, ls);
    float w = __expf(ls - nm);
    float f = __expf(m - nm);
    l = l * f + w;
#pragma unroll
    for (int d = 0; d < 32; d += 4) {
      float4 v4 = *(const float4*)&vs[j][d];
      acc[d + 0] = fmaf(acc[d + 0], f, w * v4.x);
      acc[d + 1] = fmaf(acc[d + 1], f, w * v4.y);
      acc[d + 2] = fmaf(acc[d + 2], f, w * v4.z);
      acc[d + 3] = fmaf(acc[d + 3], f, w * v4.w);
    }
    m = nm;
  }
  float inv = 1.0f / l;
  unsigned short* o = AV + ((size_t)(i * kB + b)) * 64 + h * 32;
#pragma unroll
  for (int d = 0; d < 32; ++d) o[d] = bf16u(acc[d] * inv);
}

// -------- fp32 fallback GEMM for the small critic head --------
template <int ACTF, bool DUAL>
__global__ __launch_bounds__(256) void gemm_kernel(
    const float* __restrict__ A1, const float* __restrict__ Bm1, int K1,
    const float* __restrict__ A2, const float* __restrict__ Bm2, int K2,
    const float* __restrict__ bias, float* __restrict__ C, int Mrows, int N) {
  __shared__ float As[16][68];
  __shared__ float Bs[16][68];
  const int tid = threadIdx.x;
  const int tx = tid & 15, ty = tid >> 4;
  const int m0 = blockIdx.y * 64, n0 = blockIdx.x * 64;
  const int ar = tid >> 2, aseg = tid & 3;
  float acc[4][4] = {};
#pragma unroll
  for (int pass = 0; pass < (DUAL ? 2 : 1); ++pass) {
    const float* A = (DUAL && pass) ? A2 : A1;
    const float* Bm = (DUAL && pass) ? Bm2 : Bm1;
    const int K = (DUAL && pass) ? K2 : K1;
    for (int k0 = 0; k0 < K; k0 += 16) {
      {
        int row = m0 + ar;
        int kb = k0 + aseg * 4;
        float x0 = 0.f, x1 = 0.f, x2 = 0.f, x3 = 0.f;
        if (row < Mrows) {
          const float* ap = A + (size_t)row * K + kb;
          if (kb + 3 < K) {
            float4 t = *(const float4*)ap;
            x0 = t.x; x1 = t.y; x2 = t.z; x3 = t.w;
          } else {
            if (kb + 0 < K) x0 = ap[0];
            if (kb + 1 < K) x1 = ap[1];
            if (kb + 2 < K) x2 = ap[2];
          }
        }
        As[aseg * 4 + 0][ar] = x0;
        As[aseg * 4 + 1][ar] = x1;
        As[aseg * 4 + 2][ar] = x2;
        As[aseg * 4 + 3][ar] = x3;
      }
      {
        int krow = k0 + ty;
        int nb = n0 + tx * 4;
        float y0 = 0.f, y1 = 0.f, y2 = 0.f, y3 = 0.f;
        if (krow < K) {
          const float* bp = Bm + (size_t)krow * N + nb;
          if (nb + 3 < N) {
            float4 t = *(const float4*)bp;
            y0 = t.x; y1 = t.y; y2 = t.z; y3 = t.w;
          } else {
            if (nb + 0 < N) y0 = bp[0];
            if (nb + 1 < N) y1 = bp[1];
            if (nb + 2 < N) y2 = bp[2];
          }
        }
        *(float4*)&Bs[ty][tx * 4] = make_float4(y0, y1, y2, y3);
      }
      __syncthreads();
#pragma unroll
      for (int kk = 0; kk < 16; ++kk) {
        float a[4], bb[4];
        *(float4*)a = *(const float4*)&As[kk][ty * 4];
        *(float4*)bb = *(const float4*)&Bs[kk][tx * 4];
#pragma unroll
        for (int i = 0; i < 4; ++i)
#pragma unroll
          for (int j = 0; j < 4; ++j) acc[i][j] = fmaf(a[i], bb[j], acc[i][j]);
      }
      __syncthreads();
    }
  }
#pragma unroll
  for (int i = 0; i < 4; ++i) {
    int m = m0 + ty * 4 + i;
    if (m >= Mrows) continue;
#pragma unroll
    for (int j = 0; j < 4; ++j) {
      int n = n0 + tx * 4 + j;
      if (n >= N) continue;
      float val = acc[i][j];
      if (bias) val += bias[n];
      if (ACTF == 1) val = fmaxf(val, 0.f);
      C[(size_t)m * N + n] = val;
    }
  }
}

}  // namespace

extern "C" void kernel_launch(void* const* d_in, const int* in_sizes, int n_in,
                              void* d_out, int out_size, void* d_ws, size_t ws_size,
                              hipStream_t stream) {
  (void)in_sizes; (void)n_in; (void)out_size;
  const float* aug    = (const float*)d_in[0];
  const float* action = (const float*)d_in[1];
  const float* memory = (const float*)d_in[2];
  const float* W_q    = (const float*)d_in[3];
  const float* W_kv   = (const float*)d_in[4];
  const float* W_p    = (const float*)d_in[5];
  const float* W_out  = (const float*)d_in[6];
  const float* u      = (const float*)d_in[7];
  const float* v      = (const float*)d_in[8];
  const float* ln1_g  = (const float*)d_in[9];
  const float* ln1_b  = (const float*)d_in[10];
  const float* ln2_g  = (const float*)d_in[11];
  const float* ln2_b  = (const float*)d_in[12];
  const float* ff_W1  = (const float*)d_in[13];
  const float* ff_b1  = (const float*)d_in[14];
  const float* ff_W2  = (const float*)d_in[15];
  const float* ff_b2  = (const float*)d_in[16];
  const float* g1_W   = (const float*)d_in[17];
  const float* g1_b   = (const float*)d_in[18];
  const float* g2_W   = (const float*)d_in[19];
  const float* g2_b   = (const float*)d_in[20];
  const float* d1_W   = (const float*)d_in[21];
  const float* d1_b   = (const float*)d_in[22];
  const float* d2_W   = (const float*)d_in[23];
  const float* d2_b   = (const float*)d_in[24];
  const float* d3_W   = (const float*)d_in[25];
  const float* d3_b   = (const float*)d_in[26];
  const float* d4_W   = (const float*)d_in[27];
  const float* d4_b   = (const float*)d_in[28];
  float* out = (float*)d_out;

  // ---------------- workspace carve ----------------
  char* base = (char*)d_ws;
  auto alloc = [&](size_t bytes) -> char* {
    char* p = base;
    base += (bytes + 255) & ~(size_t)255;
    return p;
  };
  unsigned short* Wqt  = (unsigned short*)alloc((size_t)64 * 512 * 2);
  unsigned short* Wkvt = (unsigned short*)alloc((size_t)128 * 512 * 2);
  unsigned short* Wot  = (unsigned short*)alloc((size_t)512 * 64 * 2);
  unsigned short* Wf1t = (unsigned short*)alloc((size_t)64 * 512 * 2);
  unsigned short* Wf2t = (unsigned short*)alloc((size_t)512 * 64 * 2);
  unsigned short* G1t  = (unsigned short*)alloc((size_t)6 * 512 * 512 * 2);
  unsigned short* G2t  = (unsigned short*)alloc((size_t)6 * 512 * 512 * 2);
  unsigned short* Memb = (unsigned short*)alloc((size_t)3072 * 512 * 2);
  unsigned short* KVb  = (unsigned short*)alloc((size_t)kJ * kB * 128 * 2);
  float* Qb  = (float*)alloc((size_t)kTB * 64 * 4);
  unsigned short* AVb = (unsigned short*)alloc((size_t)kTB * 64 * 2);
  unsigned short* Xb  = (unsigned short*)alloc((size_t)kTB * kD * 2);  // raw aug bf16
  float* Pb  = (float*)alloc((size_t)kJ * 64 * 4);
  float* TSb = (float*)alloc((size_t)kB * kD * 4);
  float* H1b = (float*)alloc((size_t)kB * 1024 * 4);
  float* H2b = (float*)alloc((size_t)kB * 512 * 4);
  float* H3b = (float*)alloc((size_t)kB * 320 * 4);
  size_t fixedBytes = (size_t)(base - (char*)d_ws);
  const size_t ln1Bytes = (size_t)kTB * kD * 2;  // L1b overlaps chunk region
  int nch = 1;
  while (nch < 32) {
    size_t chunkBytes = (size_t)(kTB / nch) * 4224 + 4096;
    size_t reuse = chunkBytes > ln1Bytes ? chunkBytes : ln1Bytes;
    if (fixedBytes + reuse <= ws_size) break;
    nch <<= 1;
  }
  const int CR = kTB / nch;
  char* R = base;
  unsigned short* L1b = (unsigned short*)R;  // ln1(aug) bf16 (dead before chunks)
  char* rp = R;
  auto ralloc = [&](size_t bytes) -> char* {
    char* p = rp;
    rp += (bytes + 255) & ~(size_t)255;
    return p;
  };
  unsigned short* Ycb   = (unsigned short*)ralloc((size_t)CR * 512 * 2);
  unsigned short* RXcb  = (unsigned short*)ralloc((size_t)CR * 512 * 2);
  unsigned short* SRCcb = (unsigned short*)ralloc((size_t)CR * 512 * 2);
  unsigned short* LN2cb = (unsigned short*)ralloc((size_t)CR * 512 * 2);
  unsigned short* F1cb  = (unsigned short*)ralloc((size_t)CR * 64 * 2);

  const float* np = nullptr;
  const int MG = CR / 128;  // m-groups per chunk (divisible by 8 for nch<=32)

  // -------- prep --------
  hipMemsetAsync(TSb, 0, (size_t)kB * kD * sizeof(float), stream);
  transp_kernel<<<dim3(2, 16, 1), 256, 0, stream>>>(W_q, Wqt, 512, 64);
  transp_kernel<<<dim3(4, 16, 1), 256, 0, stream>>>(W_kv, Wkvt, 512, 128);
  transp_kernel<<<dim3(16, 2, 1), 256, 0, stream>>>(W_out, Wot, 64, 512);
  transp_kernel<<<dim3(2, 16, 1), 256, 0, stream>>>(ff_W1, Wf1t, 512, 64);
  transp_kernel<<<dim3(16, 2, 1), 256, 0, stream>>>(ff_W2, Wf2t, 64, 512);
  transp_kernel<<<dim3(16, 16, 6), 256, 0, stream>>>(g1_W, G1t, 512, 512);
  transp_kernel<<<dim3(16, 16, 6), 256, 0, stream>>>(g2_W, G2t, 512, 512);
  conv_bf16_kernel<<<(3072 * 512 / 8 + 255) / 256, 256, 0, stream>>>(
      memory, Memb, (size_t)3072 * 512);
  // ln1(aug) -> L1b bf16 and raw aug -> Xb bf16 (one fp32 read)
  ln1_dual_kernel<<<kTB / 4, 256, 0, stream>>>(aug, ln1_g, ln1_b, L1b, Xb, kTB);
  // kv = [memory; ln1] @ W_kv  (bf16 out)
  mfma_gemm_bt<128, 1><<<dim3(1, 3072 / 128), 256, 0, stream>>>(
      Memb, Wkvt, 512, np, KVb, 128);
  mfma_gemm_bt<128, 1><<<dim3(1, kTB / 128), 256, 0, stream>>>(
      L1b, Wkvt, 512, np, KVb + (size_t)3072 * 128, 128);
  // q = ln1 @ W_q (fp32 out)
  mfma_gemm_bt<64, 0><<<dim3(1, kTB / 128), 256, 0, stream>>>(
      L1b, Wqt, 512, np, Qb, 64);
  posp_kernel<<<kJ, 64, 0, stream>>>(W_p, Pb);
  attn_kernel<<<dim3(kB, kH), 128, 0, stream>>>(Qb, KVb, Pb, u, v, AVb);

  for (int c = 0; c < nch; ++c) {
    const int R0 = c * CR;
    const unsigned short* Xc = Xb + (size_t)R0 * kD;
    // y1 = av @ W_out (bf16 out)
    mfma_gemm_bt<128, 1><<<dim3(4, MG), 256, 0, stream>>>(
        AVb + (size_t)R0 * 64, Wot, 64, np, Ycb, 512);
    // gate1 (XCD-swizzled 1-D grids)
    mfma_gate_r<<<2 * MG, 512, 0, stream>>>(Ycb, Xc, G1t, g1_b, RXcb);
    mfma_gate_hz<false><<<4 * MG, 512, 0, stream>>>(
        Ycb, RXcb, Xc, G1t, g1_b, SRCcb, nullptr, R0);
    // ln2 (bf16 in/out)
    ln_b16_kernel<<<CR / 4, 256, 0, stream>>>(SRCcb, ln2_g, ln2_b, LN2cb, CR);
    // ff1 = relu(ln2 @ ff_W1 + b1) (bf16 out)
    mfma_gemm_bt<64, 2><<<dim3(1, MG), 256, 0, stream>>>(
        LN2cb, Wf1t, 512, ff_b1, F1cb, 64);
    // y2 = ff1 @ ff_W2 + b2 (bf16 out)
    mfma_gemm_bt<128, 3><<<dim3(4, MG), 256, 0, stream>>>(
        F1cb, Wf2t, 64, ff_b2, Ycb, 512);
    // gate2 + fused mean-pool
    mfma_gate_r<<<2 * MG, 512, 0, stream>>>(Ycb, SRCcb, G2t, g2_b, RXcb);
    mfma_gate_hz<true><<<4 * MG, 512, 0, stream>>>(
        Ycb, RXcb, SRCcb, G2t, g2_b, nullptr, TSb, R0);
  }

  // critic head (fp32)
  gemm_kernel<1, false><<<dim3(16, kB / 64), 256, 0, stream>>>(
      TSb, d1_W, 512, np, np, 0, d1_b, H1b, kB, 1024);
  gemm_kernel<1, true><<<dim3(8, kB / 64), 256, 0, stream>>>(
      H1b, d2_W, 1024, action, d2_W + (size_t)1024 * 512, 64, d2_b, H2b, kB, 512);
  gemm_kernel<1, false><<<dim3(5, kB / 64), 256, 0, stream>>>(
      H2b, d3_W, 512, np, np, 0, d3_b, H3b, kB, 300);
  gemm_kernel<1, false><<<dim3(1, kB / 64), 256, 0, stream>>>(
      H3b, d4_W, 300, np, np, 0, d4_b, out, kB, 1);
}